// Round 1
// baseline (2029.942 us; speedup 1.0000x reference)
//
#include <hip/hip_runtime.h>
#include <math.h>

#define H 128
#define NNODE 50000
#define NEDGE 800000

// ---------------------------------------------------------------------------
// encode: out[N,128] = relu(x[N,K] @ w[K,128] + b)
// block = 256 threads, 8 rows/block, each thread computes 4 (row,col) outputs
// ---------------------------------------------------------------------------
template <int K>
__global__ void encode_kernel(const float* __restrict__ x, const float* __restrict__ w,
                              const float* __restrict__ b, float* __restrict__ out, int N) {
    __shared__ float xs[8 * K];
    const int tx = threadIdx.x;
    const int rowbase = blockIdx.x * 8;
    for (int i = tx; i < 8 * K; i += 256) {
        int r = i / K, c = i % K;           // K is pow2 constexpr -> shifts
        int row = rowbase + r;
        xs[i] = (row < N) ? x[(size_t)row * K + c] : 0.f;
    }
    __syncthreads();
    const int col = tx & 127, rsub = tx >> 7;  // rsub in {0,1}; rows rsub*4..rsub*4+3
    float a0 = b[col], a1 = a0, a2 = a0, a3 = a0;
#pragma unroll 4
    for (int k = 0; k < K; ++k) {
        float wv = w[k * H + col];
        a0 += xs[(rsub * 4 + 0) * K + k] * wv;
        a1 += xs[(rsub * 4 + 1) * K + k] * wv;
        a2 += xs[(rsub * 4 + 2) * K + k] * wv;
        a3 += xs[(rsub * 4 + 3) * K + k] * wv;
    }
    float acc[4] = {a0, a1, a2, a3};
#pragma unroll
    for (int j = 0; j < 4; ++j) {
        int row = rowbase + rsub * 4 + j;
        if (row < N) out[(size_t)row * H + col] = fmaxf(acc[j], 0.f);
    }
}

// ---------------------------------------------------------------------------
// degree count: cnt[dst[e]] += 1
// ---------------------------------------------------------------------------
__global__ void count_kernel(const int* __restrict__ edst, int* __restrict__ cnt, int E) {
    int e = blockIdx.x * 256 + threadIdx.x;
    if (e < E) atomicAdd(&cnt[edst[e]], 1);
}

// ---------------------------------------------------------------------------
// scatter-add of src rows onto agg (fp32 atomics). idx = e*128 + c
// ---------------------------------------------------------------------------
__global__ void scatter_kernel(const float* __restrict__ xsrc, const int* __restrict__ esrc,
                               const int* __restrict__ edst, float* __restrict__ agg, int E) {
    int idx = blockIdx.x * 256 + threadIdx.x;
    int e = idx >> 7, c = idx & 127;
    if (e < E) {
        int s = esrc[e], d = edst[e];
        atomicAdd(&agg[(size_t)d * H + c], xsrc[(size_t)s * H + c]);
    }
}

// ---------------------------------------------------------------------------
// SAGE: out = relu( l2norm( (agg/cnt) @ wl + bl + xdst @ wr ) ) [+ xdst if residual]
// block = 256, 8 rows/block
// ---------------------------------------------------------------------------
__global__ void sage_kernel(const float* __restrict__ agg, const int* __restrict__ cnt,
                            const float* __restrict__ xdst,
                            const float* __restrict__ wl, const float* __restrict__ bl,
                            const float* __restrict__ wr,
                            float* __restrict__ out, int N, int residual) {
    __shared__ float as[8 * H];
    __shared__ float xs[8 * H];
    __shared__ float os[8 * H];
    __shared__ float scl[8];
    const int tx = threadIdx.x;
    const int rowbase = blockIdx.x * 8;

    for (int i = tx; i < 8 * H; i += 256) {
        int r = i >> 7, c = i & 127;
        int row = rowbase + r;
        if (row < N) {
            float inv = 1.f / fmaxf((float)cnt[row], 1.f);
            as[i] = agg[(size_t)row * H + c] * inv;
            xs[i] = xdst[(size_t)row * H + c];
        } else {
            as[i] = 0.f;
            xs[i] = 0.f;
        }
    }
    __syncthreads();

    const int col = tx & 127, rsub = tx >> 7;
    float a0 = bl[col], a1 = a0, a2 = a0, a3 = a0;
#pragma unroll 4
    for (int k = 0; k < H; ++k) {
        float wlv = wl[k * H + col];
        float wrv = wr[k * H + col];
        a0 += as[(rsub * 4 + 0) * H + k] * wlv + xs[(rsub * 4 + 0) * H + k] * wrv;
        a1 += as[(rsub * 4 + 1) * H + k] * wlv + xs[(rsub * 4 + 1) * H + k] * wrv;
        a2 += as[(rsub * 4 + 2) * H + k] * wlv + xs[(rsub * 4 + 2) * H + k] * wrv;
        a3 += as[(rsub * 4 + 3) * H + k] * wlv + xs[(rsub * 4 + 3) * H + k] * wrv;
    }
    os[(rsub * 4 + 0) * H + col] = a0;
    os[(rsub * 4 + 1) * H + col] = a1;
    os[(rsub * 4 + 2) * H + col] = a2;
    os[(rsub * 4 + 3) * H + col] = a3;
    __syncthreads();

    {
        int r = tx >> 5, i = tx & 31;   // 8 groups of 32 threads, one row each
        float p = 0.f;
#pragma unroll
        for (int c = i; c < H; c += 32) {
            float v = os[r * H + c];
            p += v * v;
        }
#pragma unroll
        for (int off = 16; off > 0; off >>= 1) p += __shfl_down(p, off, 32);
        if (i == 0) scl[r] = 1.f / fmaxf(sqrtf(p), 1e-12f);
    }
    __syncthreads();

#pragma unroll
    for (int j = 0; j < 4; ++j) {
        int r = rsub * 4 + j;
        int row = rowbase + r;
        if (row < N) {
            float v = fmaxf(os[r * H + col] * scl[r], 0.f);
            if (residual) v += xs[r * H + col];
            out[(size_t)row * H + col] = v;
        }
    }
}

// ---------------------------------------------------------------------------
// a += b (float4)
// ---------------------------------------------------------------------------
__global__ void add_kernel(float* __restrict__ a, const float* __restrict__ b, int n4) {
    int i = blockIdx.x * 256 + threadIdx.x;
    if (i < n4) {
        float4 av = ((float4*)a)[i];
        float4 bv = ((const float4*)b)[i];
        av.x += bv.x; av.y += bv.y; av.z += bv.z; av.w += bv.w;
        ((float4*)a)[i] = av;
    }
}

// ---------------------------------------------------------------------------
// head: z = relu(hu @ w1[128,64] + b1); out = z @ w2[64,8] + b2
// block = 256 = 4 rows x 64 cols
// ---------------------------------------------------------------------------
__global__ void head_kernel(const float* __restrict__ hu,
                            const float* __restrict__ w1, const float* __restrict__ b1,
                            const float* __restrict__ w2, const float* __restrict__ b2,
                            float* __restrict__ out, int N) {
    __shared__ float hus[4 * 128];
    __shared__ float zs[4 * 64];
    const int tx = threadIdx.x;
    const int rowbase = blockIdx.x * 4;
    for (int i = tx; i < 4 * 128; i += 256) {
        int r = i >> 7, c = i & 127;
        int row = rowbase + r;
        hus[i] = (row < N) ? hu[(size_t)row * H + c] : 0.f;
    }
    __syncthreads();
    {
        int r = tx >> 6, col = tx & 63;
        float acc = b1[col];
#pragma unroll 4
        for (int k = 0; k < 128; ++k) acc += hus[r * 128 + k] * w1[k * 64 + col];
        zs[r * 64 + col] = fmaxf(acc, 0.f);
    }
    __syncthreads();
    if (tx < 32) {
        int r = tx >> 3, col = tx & 7;
        int row = rowbase + r;
        if (row < N) {
            float acc = b2[col];
#pragma unroll
            for (int k = 0; k < 64; ++k) acc += zs[r * 64 + k] * w2[k * 8 + col];
            out[(size_t)row * 8 + col] = acc;
        }
    }
}

// ---------------------------------------------------------------------------
extern "C" void kernel_launch(void* const* d_in, const int* in_sizes, int n_in,
                              void* d_out, int out_size, void* d_ws, size_t ws_size,
                              hipStream_t stream) {
    const float* x_user     = (const float*)d_in[0];   // [50000,64]
    const float* x_item     = (const float*)d_in[1];   // [50000,32]
    const int*   ei_u2i     = (const int*)d_in[2];     // [2,800000]
    const int*   ei_i2u     = (const int*)d_in[3];
    const float* enc_user_w = (const float*)d_in[4];
    const float* enc_user_b = (const float*)d_in[5];
    const float* enc_item_w = (const float*)d_in[6];
    const float* enc_item_b = (const float*)d_in[7];
    const float* W[12];
    for (int i = 0; i < 12; ++i) W[i] = (const float*)d_in[8 + i];
    const float* head_w1 = (const float*)d_in[20];
    const float* head_b1 = (const float*)d_in[21];
    const float* head_w2 = (const float*)d_in[22];
    const float* head_b2 = (const float*)d_in[23];
    float* out = (float*)d_out;

    const size_t S = (size_t)NNODE * H;  // floats per node-feature buffer
    float* hu   = (float*)d_ws;
    float* hi   = hu + S;
    float* agg  = hi + S;
    float* bufA = agg + S;
    int*   cnt_i = (int*)(bufA + S);
    int*   cnt_u = cnt_i + NNODE;

    // encoders
    encode_kernel<64><<<(NNODE + 7) / 8, 256, 0, stream>>>(x_user, enc_user_w, enc_user_b, hu, NNODE);
    encode_kernel<32><<<(NNODE + 7) / 8, 256, 0, stream>>>(x_item, enc_item_w, enc_item_b, hi, NNODE);

    // degree counts (same edge index reused by both layers)
    hipMemsetAsync(cnt_i, 0, NNODE * sizeof(int), stream);
    hipMemsetAsync(cnt_u, 0, NNODE * sizeof(int), stream);
    count_kernel<<<(NEDGE + 255) / 256, 256, 0, stream>>>(ei_u2i + NEDGE, cnt_i, NEDGE);
    count_kernel<<<(NEDGE + 255) / 256, 256, 0, stream>>>(ei_i2u + NEDGE, cnt_u, NEDGE);

    const int scatter_blocks = (NEDGE * H) / 256;  // 400000
    const int sage_blocks = (NNODE + 7) / 8;

    for (int l = 0; l < 2; ++l) {
        const float* wl_ui = W[l * 6 + 0];
        const float* bl_ui = W[l * 6 + 1];
        const float* wr_ui = W[l * 6 + 2];
        const float* wl_iu = W[l * 6 + 3];
        const float* bl_iu = W[l * 6 + 4];
        const float* wr_iu = W[l * 6 + 5];

        // new_hi -> bufA  (uses old hu, old hi)
        hipMemsetAsync(agg, 0, S * sizeof(float), stream);
        scatter_kernel<<<scatter_blocks, 256, 0, stream>>>(hu, ei_u2i, ei_u2i + NEDGE, agg, NEDGE);
        sage_kernel<<<sage_blocks, 256, 0, stream>>>(agg, cnt_i, hi, wl_ui, bl_ui, wr_ui, bufA, NNODE, 0);

        // new_hu (+ residual) -> hu in place  (uses old hi, old hu)
        hipMemsetAsync(agg, 0, S * sizeof(float), stream);
        scatter_kernel<<<scatter_blocks, 256, 0, stream>>>(hi, ei_i2u, ei_i2u + NEDGE, agg, NEDGE);
        sage_kernel<<<sage_blocks, 256, 0, stream>>>(agg, cnt_u, hu, wl_iu, bl_iu, wr_iu, hu, NNODE, 1);

        // hi += new_hi
        add_kernel<<<(int)(S / 4 + 255) / 256, 256, 0, stream>>>(hi, bufA, (int)(S / 4));
    }

    head_kernel<<<(NNODE + 3) / 4, 256, 0, stream>>>(hu, head_w1, head_b1, head_w2, head_b2, out, NNODE);
}

// Round 2
// 967.408 us; speedup vs baseline: 2.0983x; 2.0983x over previous
//
#include <hip/hip_runtime.h>
#include <math.h>

#define H 128
#define NNODE 50000
#define NEDGE 800000

// ---------------------------------------------------------------------------
// encode: out[N,128] = relu(x[N,K] @ w[K,128] + b)
// ---------------------------------------------------------------------------
template <int K>
__global__ void encode_kernel(const float* __restrict__ x, const float* __restrict__ w,
                              const float* __restrict__ b, float* __restrict__ out, int N) {
    __shared__ float xs[8 * K];
    const int tx = threadIdx.x;
    const int rowbase = blockIdx.x * 8;
    for (int i = tx; i < 8 * K; i += 256) {
        int r = i / K, c = i % K;
        int row = rowbase + r;
        xs[i] = (row < N) ? x[(size_t)row * K + c] : 0.f;
    }
    __syncthreads();
    const int col = tx & 127, rsub = tx >> 7;
    float a0 = b[col], a1 = a0, a2 = a0, a3 = a0;
#pragma unroll 4
    for (int k = 0; k < K; ++k) {
        float wv = w[k * H + col];
        a0 += xs[(rsub * 4 + 0) * K + k] * wv;
        a1 += xs[(rsub * 4 + 1) * K + k] * wv;
        a2 += xs[(rsub * 4 + 2) * K + k] * wv;
        a3 += xs[(rsub * 4 + 3) * K + k] * wv;
    }
    float acc[4] = {a0, a1, a2, a3};
#pragma unroll
    for (int j = 0; j < 4; ++j) {
        int row = rowbase + rsub * 4 + j;
        if (row < N) out[(size_t)row * H + col] = fmaxf(acc[j], 0.f);
    }
}

// ---------------------------------------------------------------------------
// CSR construction: count -> scan (3 kernels) -> fill
// ---------------------------------------------------------------------------
__global__ void count_kernel(const int* __restrict__ edst, int* __restrict__ cnt, int E) {
    int e = blockIdx.x * 256 + threadIdx.x;
    if (e < E) atomicAdd(&cnt[edst[e]], 1);
}

// block = 256 threads x 4 elems = 1024 per block
__global__ void scan1_kernel(const int* __restrict__ cnt, int* __restrict__ off,
                             int* __restrict__ bsum, int N) {
    __shared__ int tmp[256];
    const int tx = threadIdx.x;
    const int base = blockIdx.x * 1024;
    int v[4];
    int s = 0;
#pragma unroll
    for (int k = 0; k < 4; ++k) {
        int i = base + tx * 4 + k;
        v[k] = (i < N) ? cnt[i] : 0;
        s += v[k];
    }
    tmp[tx] = s;
    __syncthreads();
    for (int o = 1; o < 256; o <<= 1) {
        int t = (tx >= o) ? tmp[tx - o] : 0;
        __syncthreads();
        tmp[tx] += t;
        __syncthreads();
    }
    int excl = (tx == 0) ? 0 : tmp[tx - 1];
#pragma unroll
    for (int k = 0; k < 4; ++k) {
        int i = base + tx * 4 + k;
        if (i < N) off[i] = excl;
        excl += v[k];
    }
    if (tx == 255) bsum[blockIdx.x] = tmp[255];
}

__global__ void scan2_kernel(int* __restrict__ bsum, int nb) {
    if (threadIdx.x == 0) {
        int s = 0;
        for (int i = 0; i < nb; ++i) { int v = bsum[i]; bsum[i] = s; s += v; }
    }
}

__global__ void scan3_kernel(int* __restrict__ off, int* __restrict__ cursor,
                             const int* __restrict__ bsum, int N) {
    int i = blockIdx.x * 256 + threadIdx.x;
    if (i < N) {
        int o = off[i] + bsum[i >> 10];
        off[i] = o;
        cursor[i] = o;
    }
}

__global__ void fill_kernel(const int* __restrict__ esrc, const int* __restrict__ edst,
                            int* __restrict__ cursor, int* __restrict__ srcidx, int E) {
    int e = blockIdx.x * 256 + threadIdx.x;
    if (e < E) {
        int pos = atomicAdd(&cursor[edst[e]], 1);
        srcidx[pos] = esrc[e];
    }
}

// ---------------------------------------------------------------------------
// fused gather + SAGE:
// out = relu( l2norm( mean_gather(xsrc) @ wl + bl + xdst @ wr ) ) [+ xdst]
// block = 256 (4 waves), 8 rows/block; each wave gathers 2 rows.
// ---------------------------------------------------------------------------
__global__ void sage_gather_kernel(const float* __restrict__ xsrc,
                                   const int* __restrict__ srcidx,
                                   const int* __restrict__ off, const int* __restrict__ cnt,
                                   const float* __restrict__ xdst,
                                   const float* __restrict__ wl, const float* __restrict__ bl,
                                   const float* __restrict__ wr,
                                   float* __restrict__ out, int N, int residual) {
    __shared__ float as[8 * H];
    __shared__ float xs[8 * H];
    __shared__ float os[8 * H];
    __shared__ float scl[8];
    const int tx = threadIdx.x;
    const int rowbase = blockIdx.x * 8;

    // load xdst tile
    for (int i = tx; i < 8 * H; i += 256) {
        int r = i >> 7, c = i & 127;
        int row = rowbase + r;
        xs[i] = (row < N) ? xdst[(size_t)row * H + c] : 0.f;
    }

    // gather-mean into as: wave w handles rows 2w, 2w+1; lane covers 2 cols
    const int wave = tx >> 6, lane = tx & 63;
#pragma unroll
    for (int rr = 0; rr < 2; ++rr) {
        const int r = wave * 2 + rr;
        const int row = rowbase + r;
        float a0 = 0.f, a1 = 0.f;
        if (row < N) {
            const int start = off[row];
            const int deg = cnt[row];
            int j = 0;
            for (; j + 2 <= deg; j += 2) {
                int s0 = srcidx[start + j];
                int s1 = srcidx[start + j + 1];
                float2 v0 = ((const float2*)xsrc)[(size_t)s0 * 64 + lane];
                float2 v1 = ((const float2*)xsrc)[(size_t)s1 * 64 + lane];
                a0 += v0.x + v1.x;
                a1 += v0.y + v1.y;
            }
            if (j < deg) {
                int s = srcidx[start + j];
                float2 v = ((const float2*)xsrc)[(size_t)s * 64 + lane];
                a0 += v.x;
                a1 += v.y;
            }
            float inv = 1.f / fmaxf((float)deg, 1.f);
            a0 *= inv;
            a1 *= inv;
        }
        as[r * H + lane * 2] = a0;       // stride-2: 2-way bank alias, free
        as[r * H + lane * 2 + 1] = a1;
    }
    __syncthreads();

    const int col = tx & 127, rsub = tx >> 7;
    float a0 = bl[col], a1 = a0, a2 = a0, a3 = a0;
#pragma unroll 4
    for (int k = 0; k < H; ++k) {
        float wlv = wl[k * H + col];
        float wrv = wr[k * H + col];
        a0 += as[(rsub * 4 + 0) * H + k] * wlv + xs[(rsub * 4 + 0) * H + k] * wrv;
        a1 += as[(rsub * 4 + 1) * H + k] * wlv + xs[(rsub * 4 + 1) * H + k] * wrv;
        a2 += as[(rsub * 4 + 2) * H + k] * wlv + xs[(rsub * 4 + 2) * H + k] * wrv;
        a3 += as[(rsub * 4 + 3) * H + k] * wlv + xs[(rsub * 4 + 3) * H + k] * wrv;
    }
    os[(rsub * 4 + 0) * H + col] = a0;
    os[(rsub * 4 + 1) * H + col] = a1;
    os[(rsub * 4 + 2) * H + col] = a2;
    os[(rsub * 4 + 3) * H + col] = a3;
    __syncthreads();

    {
        int r = tx >> 5, i = tx & 31;
        float p = 0.f;
#pragma unroll
        for (int c = i; c < H; c += 32) {
            float v = os[r * H + c];
            p += v * v;
        }
#pragma unroll
        for (int o = 16; o > 0; o >>= 1) p += __shfl_down(p, o, 32);
        if (i == 0) scl[r] = 1.f / fmaxf(sqrtf(p), 1e-12f);
    }
    __syncthreads();

#pragma unroll
    for (int j = 0; j < 4; ++j) {
        int r = rsub * 4 + j;
        int row = rowbase + r;
        if (row < N) {
            float v = fmaxf(os[r * H + col] * scl[r], 0.f);
            if (residual) v += xs[r * H + col];
            out[(size_t)row * H + col] = v;
        }
    }
}

// ---------------------------------------------------------------------------
__global__ void add_kernel(float* __restrict__ a, const float* __restrict__ b, int n4) {
    int i = blockIdx.x * 256 + threadIdx.x;
    if (i < n4) {
        float4 av = ((float4*)a)[i];
        float4 bv = ((const float4*)b)[i];
        av.x += bv.x; av.y += bv.y; av.z += bv.z; av.w += bv.w;
        ((float4*)a)[i] = av;
    }
}

// ---------------------------------------------------------------------------
__global__ void head_kernel(const float* __restrict__ hu,
                            const float* __restrict__ w1, const float* __restrict__ b1,
                            const float* __restrict__ w2, const float* __restrict__ b2,
                            float* __restrict__ out, int N) {
    __shared__ float hus[4 * 128];
    __shared__ float zs[4 * 64];
    const int tx = threadIdx.x;
    const int rowbase = blockIdx.x * 4;
    for (int i = tx; i < 4 * 128; i += 256) {
        int r = i >> 7, c = i & 127;
        int row = rowbase + r;
        hus[i] = (row < N) ? hu[(size_t)row * H + c] : 0.f;
    }
    __syncthreads();
    {
        int r = tx >> 6, col = tx & 63;
        float acc = b1[col];
#pragma unroll 4
        for (int k = 0; k < 128; ++k) acc += hus[r * 128 + k] * w1[k * 64 + col];
        zs[r * 64 + col] = fmaxf(acc, 0.f);
    }
    __syncthreads();
    if (tx < 32) {
        int r = tx >> 3, col = tx & 7;
        int row = rowbase + r;
        if (row < N) {
            float acc = b2[col];
#pragma unroll
            for (int k = 0; k < 64; ++k) acc += zs[r * 64 + k] * w2[k * 8 + col];
            out[(size_t)row * 8 + col] = acc;
        }
    }
}

// ---------------------------------------------------------------------------
extern "C" void kernel_launch(void* const* d_in, const int* in_sizes, int n_in,
                              void* d_out, int out_size, void* d_ws, size_t ws_size,
                              hipStream_t stream) {
    const float* x_user     = (const float*)d_in[0];
    const float* x_item     = (const float*)d_in[1];
    const int*   ei_u2i     = (const int*)d_in[2];
    const int*   ei_i2u     = (const int*)d_in[3];
    const float* enc_user_w = (const float*)d_in[4];
    const float* enc_user_b = (const float*)d_in[5];
    const float* enc_item_w = (const float*)d_in[6];
    const float* enc_item_b = (const float*)d_in[7];
    const float* W[12];
    for (int i = 0; i < 12; ++i) W[i] = (const float*)d_in[8 + i];
    const float* head_w1 = (const float*)d_in[20];
    const float* head_b1 = (const float*)d_in[21];
    const float* head_w2 = (const float*)d_in[22];
    const float* head_b2 = (const float*)d_in[23];
    float* out = (float*)d_out;

    const size_t S = (size_t)NNODE * H;
    float* hu    = (float*)d_ws;
    float* hi    = hu + S;
    float* bufA  = hi + S;
    int*   cnt_i = (int*)(bufA + S);
    int*   cnt_u = cnt_i + NNODE;
    int*   off_i = cnt_u + NNODE;
    int*   off_u = off_i + NNODE;
    int*   cur_i = off_u + NNODE;
    int*   cur_u = cur_i + NNODE;
    int*   bsum_i = cur_u + NNODE;
    int*   bsum_u = bsum_i + 64;
    int*   src_u2i = bsum_u + 64;        // [NEDGE]
    int*   src_i2u = src_u2i + NEDGE;    // [NEDGE]

    const int NB = (NNODE + 1023) / 1024;  // 49 scan blocks

    // encoders
    encode_kernel<64><<<(NNODE + 7) / 8, 256, 0, stream>>>(x_user, enc_user_w, enc_user_b, hu, NNODE);
    encode_kernel<32><<<(NNODE + 7) / 8, 256, 0, stream>>>(x_item, enc_item_w, enc_item_b, hi, NNODE);

    // CSR build for both edge types (reused by both layers)
    hipMemsetAsync(cnt_i, 0, NNODE * sizeof(int), stream);
    hipMemsetAsync(cnt_u, 0, NNODE * sizeof(int), stream);
    count_kernel<<<(NEDGE + 255) / 256, 256, 0, stream>>>(ei_u2i + NEDGE, cnt_i, NEDGE);
    count_kernel<<<(NEDGE + 255) / 256, 256, 0, stream>>>(ei_i2u + NEDGE, cnt_u, NEDGE);
    scan1_kernel<<<NB, 256, 0, stream>>>(cnt_i, off_i, bsum_i, NNODE);
    scan1_kernel<<<NB, 256, 0, stream>>>(cnt_u, off_u, bsum_u, NNODE);
    scan2_kernel<<<1, 64, 0, stream>>>(bsum_i, NB);
    scan2_kernel<<<1, 64, 0, stream>>>(bsum_u, NB);
    scan3_kernel<<<(NNODE + 255) / 256, 256, 0, stream>>>(off_i, cur_i, bsum_i, NNODE);
    scan3_kernel<<<(NNODE + 255) / 256, 256, 0, stream>>>(off_u, cur_u, bsum_u, NNODE);
    fill_kernel<<<(NEDGE + 255) / 256, 256, 0, stream>>>(ei_u2i, ei_u2i + NEDGE, cur_i, src_u2i, NEDGE);
    fill_kernel<<<(NEDGE + 255) / 256, 256, 0, stream>>>(ei_i2u, ei_i2u + NEDGE, cur_u, src_i2u, NEDGE);

    const int sage_blocks = (NNODE + 7) / 8;

    for (int l = 0; l < 2; ++l) {
        const float* wl_ui = W[l * 6 + 0];
        const float* bl_ui = W[l * 6 + 1];
        const float* wr_ui = W[l * 6 + 2];
        const float* wl_iu = W[l * 6 + 3];
        const float* bl_iu = W[l * 6 + 4];
        const float* wr_iu = W[l * 6 + 5];

        // new_hi -> bufA  (gathers hu rows, dst = items)
        sage_gather_kernel<<<sage_blocks, 256, 0, stream>>>(
            hu, src_u2i, off_i, cnt_i, hi, wl_ui, bl_ui, wr_ui, bufA, NNODE, 0);

        // new_hu (+ residual) -> hu in place (gathers old hi rows)
        sage_gather_kernel<<<sage_blocks, 256, 0, stream>>>(
            hi, src_i2u, off_u, cnt_u, hu, wl_iu, bl_iu, wr_iu, hu, NNODE, 1);

        // hi += new_hi
        add_kernel<<<(int)(S / 4 + 255) / 256, 256, 0, stream>>>(hi, bufA, (int)(S / 4));
    }

    head_kernel<<<(NNODE + 3) / 4, 256, 0, stream>>>(hu, head_w1, head_b1, head_w2, head_b2, out, NNODE);
}

// Round 3
// 740.261 us; speedup vs baseline: 2.7422x; 1.3068x over previous
//
#include <hip/hip_runtime.h>
#include <math.h>

#define H 128
#define NNODE 50000
#define NEDGE 800000

typedef unsigned short ushortT;
typedef unsigned int uintT;
typedef __attribute__((ext_vector_type(8))) short short8;
typedef __attribute__((ext_vector_type(4))) float floatx4;

static __device__ __forceinline__ float bf2f(ushortT u) {
    union { uintT i; float f; } c; c.i = ((uintT)u) << 16; return c.f;
}
static __device__ __forceinline__ ushortT f2bf(float f) {
    union { float f; uintT i; } c; c.f = f;
    uintT lsb = (c.i >> 16) & 1;
    c.i += 0x7fffu + lsb;          // round-to-nearest-even
    return (ushortT)(c.i >> 16);
}
static __device__ __forceinline__ float lo2f(uintT v) {
    union { uintT i; float f; } c; c.i = v << 16; return c.f;
}
static __device__ __forceinline__ float hi2f(uintT v) {
    union { uintT i; float f; } c; c.i = v & 0xffff0000u; return c.f;
}
static __device__ __forceinline__ uintT pack2(float a, float b) {
    return (uintT)f2bf(a) | ((uintT)f2bf(b) << 16);
}

// ---------------------------------------------------------------------------
// encode: out[N,128] = relu(x[N,K] @ w[K,128] + b), bf16 output
// ---------------------------------------------------------------------------
template <int K>
__global__ void encode_kernel(const float* __restrict__ x, const float* __restrict__ w,
                              const float* __restrict__ b, ushortT* __restrict__ out, int N) {
    __shared__ float xs[8 * K];
    const int tx = threadIdx.x;
    const int rowbase = blockIdx.x * 8;
    for (int i = tx; i < 8 * K; i += 256) {
        int r = i / K, c = i % K;
        xs[i] = x[(size_t)(rowbase + r) * K + c];
    }
    __syncthreads();
    const int col = tx & 127, rsub = tx >> 7;
    float a0 = b[col], a1 = a0, a2 = a0, a3 = a0;
#pragma unroll 4
    for (int k = 0; k < K; ++k) {
        float wv = w[k * H + col];
        a0 += xs[(rsub * 4 + 0) * K + k] * wv;
        a1 += xs[(rsub * 4 + 1) * K + k] * wv;
        a2 += xs[(rsub * 4 + 2) * K + k] * wv;
        a3 += xs[(rsub * 4 + 3) * K + k] * wv;
    }
    float acc[4] = {a0, a1, a2, a3};
#pragma unroll
    for (int j = 0; j < 4; ++j) {
        int row = rowbase + rsub * 4 + j;
        out[(size_t)row * H + col] = f2bf(fmaxf(acc[j], 0.f));
    }
}

// ---------------------------------------------------------------------------
// weight convert + transpose: wT[c*128+k] = bf16(w[k*128+c])
// ---------------------------------------------------------------------------
__global__ void convert_wT_kernel(const float* __restrict__ w, ushortT* __restrict__ wT) {
    int t = blockIdx.x * 256 + threadIdx.x;   // 16384 threads
    int k = t >> 7, c = t & 127;
    wT[c * 128 + k] = f2bf(w[k * 128 + c]);
}

// ---------------------------------------------------------------------------
// CSR construction
// ---------------------------------------------------------------------------
__global__ void count_kernel(const int* __restrict__ edst, int* __restrict__ cnt, int E) {
    int e = blockIdx.x * 256 + threadIdx.x;
    if (e < E) atomicAdd(&cnt[edst[e]], 1);
}

__global__ void scan1_kernel(const int* __restrict__ cnt, int* __restrict__ off,
                             int* __restrict__ bsum, int N) {
    __shared__ int tmp[256];
    const int tx = threadIdx.x;
    const int base = blockIdx.x * 1024;
    int v[4];
    int s = 0;
#pragma unroll
    for (int k = 0; k < 4; ++k) {
        int i = base + tx * 4 + k;
        v[k] = (i < N) ? cnt[i] : 0;
        s += v[k];
    }
    tmp[tx] = s;
    __syncthreads();
    for (int o = 1; o < 256; o <<= 1) {
        int t = (tx >= o) ? tmp[tx - o] : 0;
        __syncthreads();
        tmp[tx] += t;
        __syncthreads();
    }
    int excl = (tx == 0) ? 0 : tmp[tx - 1];
#pragma unroll
    for (int k = 0; k < 4; ++k) {
        int i = base + tx * 4 + k;
        if (i < N) off[i] = excl;
        excl += v[k];
    }
    if (tx == 255) bsum[blockIdx.x] = tmp[255];
}

__global__ void scan2_kernel(int* __restrict__ bsum, int nb) {
    if (threadIdx.x == 0) {
        int s = 0;
        for (int i = 0; i < nb; ++i) { int v = bsum[i]; bsum[i] = s; s += v; }
    }
}

__global__ void scan3_kernel(int* __restrict__ off, int* __restrict__ cursor,
                             const int* __restrict__ bsum, int N) {
    int i = blockIdx.x * 256 + threadIdx.x;
    if (i < N) {
        int o = off[i] + bsum[i >> 10];
        off[i] = o;
        cursor[i] = o;
    }
}

__global__ void fill_kernel(const int* __restrict__ esrc, const int* __restrict__ edst,
                            int* __restrict__ cursor, int* __restrict__ srcidx, int E) {
    int e = blockIdx.x * 256 + threadIdx.x;
    if (e < E) {
        int pos = atomicAdd(&cursor[edst[e]], 1);
        srcidx[pos] = esrc[e];
    }
}

// ---------------------------------------------------------------------------
// fused gather + MFMA SAGE (bf16 features, fp32 accum):
//   out = relu( l2norm( [mean_gather(xsrc) | xdst] @ [wl;wr] + bl ) ) [+ xdst]
// block = 256 (4 waves), 16 rows/block (50000 = 16*3125, no tail).
// A tile in LDS: [16 rows][264] bf16; k 0..127 = agg, 128..255 = xdst.
// Weights pre-transposed bf16: wT[col][k], k-contiguous.
// C frag layout (16x16x32): col = lane&15, row = (lane>>4)*4 + reg.
// ---------------------------------------------------------------------------
__global__ void sage_mfma_kernel(const ushortT* __restrict__ xsrc,
                                 const int* __restrict__ srcidx,
                                 const int* __restrict__ off, const int* __restrict__ cnt,
                                 const ushortT* __restrict__ xdst,
                                 const ushortT* __restrict__ wlT, const float* __restrict__ bl,
                                 const ushortT* __restrict__ wrT,
                                 ushortT* __restrict__ out, int residual) {
    __shared__ ushortT At[16 * 264];
    __shared__ float part[4][16];
    __shared__ float scl[16];
    const int tx = threadIdx.x;
    const int rowbase = blockIdx.x * 16;
    const int wave = tx >> 6, lane = tx & 63;

    // stage xdst tile: thread t -> row t>>4, 16B chunk t&15
    {
        int r = tx >> 4, ch = tx & 15;
        *reinterpret_cast<short8*>(&At[r * 264 + 128 + ch * 8]) =
            *reinterpret_cast<const short8*>(&xdst[(size_t)(rowbase + r) * H + ch * 8]);
    }

    // gather-mean: each wave gathers 4 rows; lane covers cols 2*lane, 2*lane+1
    const uintT* src32 = (const uintT*)xsrc;
#pragma unroll
    for (int rr = 0; rr < 4; ++rr) {
        const int r = wave * 4 + rr;
        const int row = rowbase + r;
        const int start = off[row];
        const int deg = cnt[row];
        float a0 = 0.f, a1 = 0.f;
        int j = 0;
        for (; j + 2 <= deg; j += 2) {
            int s0 = srcidx[start + j];
            int s1 = srcidx[start + j + 1];
            uintT v0 = src32[(size_t)s0 * 64 + lane];
            uintT v1 = src32[(size_t)s1 * 64 + lane];
            a0 += lo2f(v0) + lo2f(v1);
            a1 += hi2f(v0) + hi2f(v1);
        }
        if (j < deg) {
            uintT v = src32[(size_t)srcidx[start + j] * 64 + lane];
            a0 += lo2f(v);
            a1 += hi2f(v);
        }
        float inv = 1.f / fmaxf((float)deg, 1.f);
        *reinterpret_cast<uintT*>(&At[r * 264 + lane * 2]) = pack2(a0 * inv, a1 * inv);
    }
    __syncthreads();

    // MFMA: wave w covers cols [32w, 32w+32); two 16-col tiles
    const int ln = lane & 15, quad = lane >> 4;
    const int n0 = wave * 32;
    floatx4 acc0 = {0.f, 0.f, 0.f, 0.f};
    floatx4 acc1 = {0.f, 0.f, 0.f, 0.f};
#pragma unroll
    for (int k0 = 0; k0 < 256; k0 += 32) {
        short8 af = *reinterpret_cast<const short8*>(&At[ln * 264 + k0 + quad * 8]);
        const ushortT* wT = (k0 < 128) ? wlT : wrT;
        const int kk = (k0 & 127) + quad * 8;
        short8 b0 = *reinterpret_cast<const short8*>(&wT[(n0 + ln) * 128 + kk]);
        short8 b1 = *reinterpret_cast<const short8*>(&wT[(n0 + 16 + ln) * 128 + kk]);
        acc0 = __builtin_amdgcn_mfma_f32_16x16x32_bf16(af, b0, acc0, 0, 0, 0);
        acc1 = __builtin_amdgcn_mfma_f32_16x16x32_bf16(af, b1, acc1, 0, 0, 0);
    }

    // epilogue: bias, row L2-norm across waves, relu, residual, bf16 store
    const float bl0 = bl[n0 + ln];
    const float bl1 = bl[n0 + 16 + ln];
    float v0[4], v1[4], s[4];
#pragma unroll
    for (int r = 0; r < 4; ++r) {
        v0[r] = acc0[r] + bl0;
        v1[r] = acc1[r] + bl1;
        s[r] = v0[r] * v0[r] + v1[r] * v1[r];
    }
#pragma unroll
    for (int m = 1; m < 16; m <<= 1) {
#pragma unroll
        for (int r = 0; r < 4; ++r) s[r] += __shfl_xor(s[r], m, 64);
    }
    if (ln == 0) {
#pragma unroll
        for (int r = 0; r < 4; ++r) part[wave][quad * 4 + r] = s[r];
    }
    __syncthreads();
    if (tx < 16) {
        float t = part[0][tx] + part[1][tx] + part[2][tx] + part[3][tx];
        scl[tx] = 1.f / fmaxf(sqrtf(t), 1e-12f);
    }
    __syncthreads();
#pragma unroll
    for (int r = 0; r < 4; ++r) {
        const int row = quad * 4 + r;
        const float sc = scl[row];
        float o0 = fmaxf(v0[r] * sc, 0.f);
        float o1 = fmaxf(v1[r] * sc, 0.f);
        if (residual) {
            o0 += bf2f(At[row * 264 + 128 + n0 + ln]);
            o1 += bf2f(At[row * 264 + 128 + n0 + 16 + ln]);
        }
        out[(size_t)(rowbase + row) * H + n0 + ln] = f2bf(o0);
        out[(size_t)(rowbase + row) * H + n0 + 16 + ln] = f2bf(o1);
    }
}

// ---------------------------------------------------------------------------
// a += b, bf16 pairs
// ---------------------------------------------------------------------------
__global__ void add_bf16_kernel(ushortT* __restrict__ a, const ushortT* __restrict__ b, int n2) {
    int i = blockIdx.x * 256 + threadIdx.x;
    if (i < n2) {
        uintT av = ((uintT*)a)[i];
        uintT bv = ((const uintT*)b)[i];
        ((uintT*)a)[i] = pack2(lo2f(av) + lo2f(bv), hi2f(av) + hi2f(bv));
    }
}

// ---------------------------------------------------------------------------
// head: z = relu(hu @ w1[128,64] + b1); out = z @ w2[64,8] + b2 (fp32 out)
// ---------------------------------------------------------------------------
__global__ void head_kernel(const ushortT* __restrict__ hu,
                            const float* __restrict__ w1, const float* __restrict__ b1,
                            const float* __restrict__ w2, const float* __restrict__ b2,
                            float* __restrict__ out, int N) {
    __shared__ float hus[4 * 128];
    __shared__ float zs[4 * 64];
    const int tx = threadIdx.x;
    const int rowbase = blockIdx.x * 4;
    for (int i = tx; i < 4 * 128; i += 256) {
        hus[i] = bf2f(hu[(size_t)(rowbase + (i >> 7)) * H + (i & 127)]);
    }
    __syncthreads();
    {
        int r = tx >> 6, col = tx & 63;
        float acc = b1[col];
#pragma unroll 4
        for (int k = 0; k < 128; ++k) acc += hus[r * 128 + k] * w1[k * 64 + col];
        zs[r * 64 + col] = fmaxf(acc, 0.f);
    }
    __syncthreads();
    if (tx < 32) {
        int r = tx >> 3, col = tx & 7;
        float acc = b2[col];
#pragma unroll
        for (int k = 0; k < 64; ++k) acc += zs[r * 64 + k] * w2[k * 8 + col];
        out[(size_t)(rowbase + r) * 8 + col] = acc;
    }
}

// ---------------------------------------------------------------------------
extern "C" void kernel_launch(void* const* d_in, const int* in_sizes, int n_in,
                              void* d_out, int out_size, void* d_ws, size_t ws_size,
                              hipStream_t stream) {
    const float* x_user     = (const float*)d_in[0];
    const float* x_item     = (const float*)d_in[1];
    const int*   ei_u2i     = (const int*)d_in[2];
    const int*   ei_i2u     = (const int*)d_in[3];
    const float* enc_user_w = (const float*)d_in[4];
    const float* enc_user_b = (const float*)d_in[5];
    const float* enc_item_w = (const float*)d_in[6];
    const float* enc_item_b = (const float*)d_in[7];
    const float* W[12];
    for (int i = 0; i < 12; ++i) W[i] = (const float*)d_in[8 + i];
    const float* head_w1 = (const float*)d_in[20];
    const float* head_b1 = (const float*)d_in[21];
    const float* head_w2 = (const float*)d_in[22];
    const float* head_b2 = (const float*)d_in[23];
    float* out = (float*)d_out;

    const size_t S = (size_t)NNODE * H;
    ushortT* hu   = (ushortT*)d_ws;
    ushortT* hi   = hu + S;
    ushortT* bufA = hi + S;
    ushortT* wT   = bufA + S;                 // 8 matrices x 16384 bf16
    int*   cnt_i  = (int*)(wT + 8 * 16384);
    int*   cnt_u  = cnt_i + NNODE;
    int*   off_i  = cnt_u + NNODE;
    int*   off_u  = off_i + NNODE;
    int*   cur_i  = off_u + NNODE;
    int*   cur_u  = cur_i + NNODE;
    int*   bsum_i = cur_u + NNODE;
    int*   bsum_u = bsum_i + 64;
    int*   src_u2i = bsum_u + 64;             // [NEDGE]
    int*   src_i2u = src_u2i + NEDGE;         // [NEDGE]

    const int NB = (NNODE + 1023) / 1024;

    // encoders (bf16 out)
    encode_kernel<64><<<NNODE / 8, 256, 0, stream>>>(x_user, enc_user_w, enc_user_b, hu, NNODE);
    encode_kernel<32><<<NNODE / 8, 256, 0, stream>>>(x_item, enc_item_w, enc_item_b, hi, NNODE);

    // weight convert+transpose: order per layer: wl_ui, wr_ui, wl_iu, wr_iu
    for (int l = 0; l < 2; ++l) {
        convert_wT_kernel<<<64, 256, 0, stream>>>(W[l * 6 + 0], wT + (l * 4 + 0) * 16384);
        convert_wT_kernel<<<64, 256, 0, stream>>>(W[l * 6 + 2], wT + (l * 4 + 1) * 16384);
        convert_wT_kernel<<<64, 256, 0, stream>>>(W[l * 6 + 3], wT + (l * 4 + 2) * 16384);
        convert_wT_kernel<<<64, 256, 0, stream>>>(W[l * 6 + 5], wT + (l * 4 + 3) * 16384);
    }

    // CSR build (shared by both layers)
    hipMemsetAsync(cnt_i, 0, NNODE * sizeof(int), stream);
    hipMemsetAsync(cnt_u, 0, NNODE * sizeof(int), stream);
    count_kernel<<<(NEDGE + 255) / 256, 256, 0, stream>>>(ei_u2i + NEDGE, cnt_i, NEDGE);
    count_kernel<<<(NEDGE + 255) / 256, 256, 0, stream>>>(ei_i2u + NEDGE, cnt_u, NEDGE);
    scan1_kernel<<<NB, 256, 0, stream>>>(cnt_i, off_i, bsum_i, NNODE);
    scan1_kernel<<<NB, 256, 0, stream>>>(cnt_u, off_u, bsum_u, NNODE);
    scan2_kernel<<<1, 64, 0, stream>>>(bsum_i, NB);
    scan2_kernel<<<1, 64, 0, stream>>>(bsum_u, NB);
    scan3_kernel<<<(NNODE + 255) / 256, 256, 0, stream>>>(off_i, cur_i, bsum_i, NNODE);
    scan3_kernel<<<(NNODE + 255) / 256, 256, 0, stream>>>(off_u, cur_u, bsum_u, NNODE);
    fill_kernel<<<(NEDGE + 255) / 256, 256, 0, stream>>>(ei_u2i, ei_u2i + NEDGE, cur_i, src_u2i, NEDGE);
    fill_kernel<<<(NEDGE + 255) / 256, 256, 0, stream>>>(ei_i2u, ei_i2u + NEDGE, cur_u, src_i2u, NEDGE);

    const int sage_blocks = NNODE / 16;  // 3125, exact

    for (int l = 0; l < 2; ++l) {
        const float* bl_ui = W[l * 6 + 1];
        const float* bl_iu = W[l * 6 + 4];
        const ushortT* wl_ui_T = wT + (l * 4 + 0) * 16384;
        const ushortT* wr_ui_T = wT + (l * 4 + 1) * 16384;
        const ushortT* wl_iu_T = wT + (l * 4 + 2) * 16384;
        const ushortT* wr_iu_T = wT + (l * 4 + 3) * 16384;

        // new_hi -> bufA (gather hu rows, dst = items)
        sage_mfma_kernel<<<sage_blocks, 256, 0, stream>>>(
            hu, src_u2i, off_i, cnt_i, hi, wl_ui_T, bl_ui, wr_ui_T, bufA, 0);

        // new_hu (+residual) -> hu in place (gather old hi rows)
        sage_mfma_kernel<<<sage_blocks, 256, 0, stream>>>(
            hi, src_i2u, off_u, cnt_u, hu, wl_iu_T, bl_iu, wr_iu_T, hu, 1);

        // hi += new_hi
        add_bf16_kernel<<<(int)(S / 2 + 255) / 256, 256, 0, stream>>>(hi, bufA, (int)(S / 2));
    }

    head_kernel<<<NNODE / 4, 256, 0, stream>>>(hu, head_w1, head_b1, head_w2, head_b2, out, NNODE);
}

// Round 4
// 560.978 us; speedup vs baseline: 3.6186x; 1.3196x over previous
//
#include <hip/hip_runtime.h>
#include <math.h>

#define H 128
#define NNODE 50000
#define NEDGE 800000
#define NBLK16 3125      // NNODE / 16
#define NB 49            // scan blocks per array (1024 elems each)

typedef unsigned short ushortT;
typedef unsigned int uintT;
typedef __attribute__((ext_vector_type(8))) short short8;
typedef __attribute__((ext_vector_type(4))) float floatx4;

static __device__ __forceinline__ float bf2f(ushortT u) {
    union { uintT i; float f; } c; c.i = ((uintT)u) << 16; return c.f;
}
static __device__ __forceinline__ ushortT f2bf(float f) {
    union { float f; uintT i; } c; c.f = f;
    uintT lsb = (c.i >> 16) & 1;
    c.i += 0x7fffu + lsb;          // round-to-nearest-even
    return (ushortT)(c.i >> 16);
}
static __device__ __forceinline__ float lo2f(uintT v) {
    union { uintT i; float f; } c; c.i = v << 16; return c.f;
}
static __device__ __forceinline__ float hi2f(uintT v) {
    union { uintT i; float f; } c; c.i = v & 0xffff0000u; return c.f;
}
static __device__ __forceinline__ uintT pack2(float a, float b) {
    return (uintT)f2bf(a) | ((uintT)f2bf(b) << 16);
}

// ---------------------------------------------------------------------------
// one-shot weight convert+transpose for all matrices (bf16, [col][k] k-contig)
// blocks 0..511: 8 HxH mats; 512..543: enc_user (64x128); 544..559: enc_item
// (32x128); 560..591: head_w1 (128x64)
// wT offsets: HxH m at m*16384; enc_user 131072; enc_item 139264; w1 143360
// ---------------------------------------------------------------------------
__global__ void convert_all_kernel(const float* __restrict__ s0, const float* __restrict__ s1,
                                   const float* __restrict__ s2, const float* __restrict__ s3,
                                   const float* __restrict__ s4, const float* __restrict__ s5,
                                   const float* __restrict__ s6, const float* __restrict__ s7,
                                   const float* __restrict__ seu, const float* __restrict__ sei,
                                   const float* __restrict__ sw1, ushortT* __restrict__ wT) {
    const int b = blockIdx.x, t = threadIdx.x;
    if (b < 512) {
        const int m = b >> 6;
        const float* s = (m == 0) ? s0 : (m == 1) ? s1 : (m == 2) ? s2 : (m == 3) ? s3
                       : (m == 4) ? s4 : (m == 5) ? s5 : (m == 6) ? s6 : s7;
        int i = (b & 63) * 256 + t;
        int k = i >> 7, c = i & 127;
        wT[m * 16384 + c * 128 + k] = f2bf(s[k * 128 + c]);
    } else if (b < 544) {
        int i = (b - 512) * 256 + t;          // 8192
        int k = i >> 7, c = i & 127;
        wT[131072 + c * 64 + k] = f2bf(seu[k * 128 + c]);
    } else if (b < 560) {
        int i = (b - 544) * 256 + t;          // 4096
        int k = i >> 7, c = i & 127;
        wT[139264 + c * 32 + k] = f2bf(sei[k * 128 + c]);
    } else {
        int i = (b - 560) * 256 + t;          // 8192
        int k = i >> 6, c = i & 63;
        wT[143360 + c * 128 + k] = f2bf(sw1[k * 64 + c]);
    }
}

// ---------------------------------------------------------------------------
// merged encoders (MFMA): blocks [0,3125) user K=64, [3125,6250) item K=32
// out = relu(x @ w + b) in bf16
// ---------------------------------------------------------------------------
__global__ void encode2_kernel(const float* __restrict__ xu, const ushortT* __restrict__ wTu,
                               const float* __restrict__ bu,
                               const float* __restrict__ xi, const ushortT* __restrict__ wTi,
                               const float* __restrict__ bi,
                               ushortT* __restrict__ outu, ushortT* __restrict__ outi) {
    __shared__ ushortT xs[16 * 72];
    const bool user = blockIdx.x < NBLK16;
    const int blk = user ? blockIdx.x : blockIdx.x - NBLK16;
    const int K = user ? 64 : 32;
    const int kshift = user ? 6 : 5;
    const int stride = K + 8;
    const float* x = user ? xu : xi;
    const ushortT* wT = user ? wTu : wTi;
    const float* bias = user ? bu : bi;
    ushortT* out = user ? outu : outi;

    const int tx = threadIdx.x;
    const int rowbase = blk * 16;

    {   // stage + fp32->bf16 convert; tile rows are contiguous in x
        int i = tx * 4;
        if (i < 16 * K) {
            const float4 v = *reinterpret_cast<const float4*>(&x[(size_t)rowbase * K + i]);
            int r = i >> kshift, c = i & (K - 1);
            uint2 w;
            w.x = pack2(v.x, v.y);
            w.y = pack2(v.z, v.w);
            *reinterpret_cast<uint2*>(&xs[r * stride + c]) = w;
        }
    }
    __syncthreads();

    const int wave = tx >> 6, lane = tx & 63;
    const int ln = lane & 15, quad = lane >> 4;
    const int n0 = wave * 32;
    floatx4 acc0 = {0.f, 0.f, 0.f, 0.f};
    floatx4 acc1 = {0.f, 0.f, 0.f, 0.f};
    for (int k0 = 0; k0 < K; k0 += 32) {
        short8 af = *reinterpret_cast<const short8*>(&xs[ln * stride + k0 + quad * 8]);
        short8 b0 = *reinterpret_cast<const short8*>(&wT[(n0 + ln) * K + k0 + quad * 8]);
        short8 b1 = *reinterpret_cast<const short8*>(&wT[(n0 + 16 + ln) * K + k0 + quad * 8]);
        acc0 = __builtin_amdgcn_mfma_f32_16x16x32_bf16(af, b0, acc0, 0, 0, 0);
        acc1 = __builtin_amdgcn_mfma_f32_16x16x32_bf16(af, b1, acc1, 0, 0, 0);
    }
    const float b0v = bias[n0 + ln], b1v = bias[n0 + 16 + ln];
#pragma unroll
    for (int r = 0; r < 4; ++r) {
        int row = rowbase + quad * 4 + r;
        out[(size_t)row * H + n0 + ln] = f2bf(fmaxf(acc0[r] + b0v, 0.f));
        out[(size_t)row * H + n0 + 16 + ln] = f2bf(fmaxf(acc1[r] + b1v, 0.f));
    }
}

// ---------------------------------------------------------------------------
// CSR construction, both edge types in one dispatch each
// ---------------------------------------------------------------------------
__global__ void count2_kernel(const int* __restrict__ e1dst, const int* __restrict__ e2dst,
                              int* __restrict__ cnt1, int* __restrict__ cnt2, int E) {
    int t = blockIdx.x * 256 + threadIdx.x;
    if (t < E) atomicAdd(&cnt1[e1dst[t]], 1);
    else atomicAdd(&cnt2[e2dst[t - E]], 1);
}

__global__ void scan1_kernel(const int* __restrict__ cnt1, int* __restrict__ off1, int* __restrict__ bsum1,
                             const int* __restrict__ cnt2, int* __restrict__ off2, int* __restrict__ bsum2,
                             int N) {
    __shared__ int tmp[256];
    const bool first = blockIdx.x < NB;
    const int blk = first ? blockIdx.x : blockIdx.x - NB;
    const int* cnt = first ? cnt1 : cnt2;
    int* off = first ? off1 : off2;
    int* bsum = first ? bsum1 : bsum2;
    const int tx = threadIdx.x;
    const int base = blk * 1024;
    int v[4];
    int s = 0;
#pragma unroll
    for (int k = 0; k < 4; ++k) {
        int i = base + tx * 4 + k;
        v[k] = (i < N) ? cnt[i] : 0;
        s += v[k];
    }
    tmp[tx] = s;
    __syncthreads();
    for (int o = 1; o < 256; o <<= 1) {
        int t = (tx >= o) ? tmp[tx - o] : 0;
        __syncthreads();
        tmp[tx] += t;
        __syncthreads();
    }
    int excl = (tx == 0) ? 0 : tmp[tx - 1];
#pragma unroll
    for (int k = 0; k < 4; ++k) {
        int i = base + tx * 4 + k;
        if (i < N) off[i] = excl;
        excl += v[k];
    }
    if (tx == 255) bsum[blk] = tmp[255];
}

__global__ void scan2_kernel(int* __restrict__ b1, int* __restrict__ b2, int nb) {
    if (threadIdx.x < 2) {
        int* b = (threadIdx.x == 0) ? b1 : b2;
        int s = 0;
        for (int i = 0; i < nb; ++i) { int v = b[i]; b[i] = s; s += v; }
    }
}

__global__ void scan3_kernel(int* __restrict__ off1, int* __restrict__ cur1, const int* __restrict__ bsum1,
                             int* __restrict__ off2, int* __restrict__ cur2, const int* __restrict__ bsum2,
                             int nblk, int N) {
    const bool first = blockIdx.x < nblk;
    const int blk = first ? blockIdx.x : blockIdx.x - nblk;
    int* off = first ? off1 : off2;
    int* cur = first ? cur1 : cur2;
    const int* bsum = first ? bsum1 : bsum2;
    int i = blk * 256 + threadIdx.x;
    if (i < N) {
        int o = off[i] + bsum[i >> 10];
        off[i] = o;
        cur[i] = o;
    }
}

__global__ void fill2_kernel(const int* __restrict__ e1, const int* __restrict__ e2,
                             int* __restrict__ cur1, int* __restrict__ cur2,
                             int* __restrict__ s1, int* __restrict__ s2, int E) {
    int t = blockIdx.x * 256 + threadIdx.x;
    if (t < E) {
        int pos = atomicAdd(&cur1[e1[E + t]], 1);
        s1[pos] = e1[t];
    } else {
        int tt = t - E;
        int pos = atomicAdd(&cur2[e2[E + tt]], 1);
        s2[pos] = e2[tt];
    }
}

// ---------------------------------------------------------------------------
// merged SAGE pair (one hetero layer, both directions) — fused gather + MFMA:
//   out = relu( l2norm( [mean_gather(xsrc) | xdst] @ [wl;wr] + bl ) ) + xdst
// blocks [0,3125): A-half (dst=items); [3125,6250): B-half (dst=users)
// ---------------------------------------------------------------------------
__global__ void sage2_kernel(
    const ushortT* __restrict__ xsrcA, const int* __restrict__ srcA,
    const int* __restrict__ offA, const int* __restrict__ cntA,
    const ushortT* __restrict__ xdstA, const ushortT* __restrict__ wlTA,
    const float* __restrict__ blA, const ushortT* __restrict__ wrTA, ushortT* __restrict__ outA,
    const ushortT* __restrict__ xsrcB, const int* __restrict__ srcB,
    const int* __restrict__ offB, const int* __restrict__ cntB,
    const ushortT* __restrict__ xdstB, const ushortT* __restrict__ wlTB,
    const float* __restrict__ blB, const ushortT* __restrict__ wrTB, ushortT* __restrict__ outB) {
    __shared__ ushortT At[16 * 264];
    __shared__ float part[4][16];
    __shared__ float scl[16];
    const bool first = blockIdx.x < NBLK16;
    const int blk = first ? blockIdx.x : blockIdx.x - NBLK16;
    const ushortT* xsrc = first ? xsrcA : xsrcB;
    const int* srcidx   = first ? srcA  : srcB;
    const int* off      = first ? offA  : offB;
    const int* cnt      = first ? cntA  : cntB;
    const ushortT* xdst = first ? xdstA : xdstB;
    const ushortT* wlT  = first ? wlTA  : wlTB;
    const float* bl     = first ? blA   : blB;
    const ushortT* wrT  = first ? wrTA  : wrTB;
    ushortT* out        = first ? outA  : outB;

    const int tx = threadIdx.x;
    const int rowbase = blk * 16;
    const int wave = tx >> 6, lane = tx & 63;

    {   // stage xdst tile into k-slots 128..255
        int r = tx >> 4, ch = tx & 15;
        *reinterpret_cast<short8*>(&At[r * 264 + 128 + ch * 8]) =
            *reinterpret_cast<const short8*>(&xdst[(size_t)(rowbase + r) * H + ch * 8]);
    }

    // gather-mean, 4 rows per wave, unroll-4 for memory-level parallelism
    const uintT* src32 = (const uintT*)xsrc;
#pragma unroll
    for (int rr = 0; rr < 4; ++rr) {
        const int r = wave * 4 + rr;
        const int row = rowbase + r;
        const int start = off[row];
        const int deg = cnt[row];
        float a0 = 0.f, a1 = 0.f;
        int j = 0;
        for (; j + 4 <= deg; j += 4) {
            int s0 = srcidx[start + j + 0];
            int s1 = srcidx[start + j + 1];
            int s2 = srcidx[start + j + 2];
            int s3 = srcidx[start + j + 3];
            uintT v0 = src32[(size_t)s0 * 64 + lane];
            uintT v1 = src32[(size_t)s1 * 64 + lane];
            uintT v2 = src32[(size_t)s2 * 64 + lane];
            uintT v3 = src32[(size_t)s3 * 64 + lane];
            a0 += (lo2f(v0) + lo2f(v1)) + (lo2f(v2) + lo2f(v3));
            a1 += (hi2f(v0) + hi2f(v1)) + (hi2f(v2) + hi2f(v3));
        }
        for (; j < deg; ++j) {
            uintT v = src32[(size_t)srcidx[start + j] * 64 + lane];
            a0 += lo2f(v);
            a1 += hi2f(v);
        }
        float inv = 1.f / fmaxf((float)deg, 1.f);
        *reinterpret_cast<uintT*>(&At[r * 264 + lane * 2]) = pack2(a0 * inv, a1 * inv);
    }
    __syncthreads();

    // MFMA: wave w -> cols [32w, 32w+32)
    const int ln = lane & 15, quad = lane >> 4;
    const int n0 = wave * 32;
    floatx4 acc0 = {0.f, 0.f, 0.f, 0.f};
    floatx4 acc1 = {0.f, 0.f, 0.f, 0.f};
#pragma unroll
    for (int k0 = 0; k0 < 256; k0 += 32) {
        short8 af = *reinterpret_cast<const short8*>(&At[ln * 264 + k0 + quad * 8]);
        const ushortT* wT = (k0 < 128) ? wlT : wrT;
        const int kk = (k0 & 127) + quad * 8;
        short8 b0 = *reinterpret_cast<const short8*>(&wT[(n0 + ln) * 128 + kk]);
        short8 b1 = *reinterpret_cast<const short8*>(&wT[(n0 + 16 + ln) * 128 + kk]);
        acc0 = __builtin_amdgcn_mfma_f32_16x16x32_bf16(af, b0, acc0, 0, 0, 0);
        acc1 = __builtin_amdgcn_mfma_f32_16x16x32_bf16(af, b1, acc1, 0, 0, 0);
    }

    // epilogue: bias, row L2-norm across waves, relu, residual(+xdst), bf16 store
    const float bl0 = bl[n0 + ln];
    const float bl1 = bl[n0 + 16 + ln];
    float v0[4], v1[4], s[4];
#pragma unroll
    for (int r = 0; r < 4; ++r) {
        v0[r] = acc0[r] + bl0;
        v1[r] = acc1[r] + bl1;
        s[r] = v0[r] * v0[r] + v1[r] * v1[r];
    }
#pragma unroll
    for (int m = 1; m < 16; m <<= 1) {
#pragma unroll
        for (int r = 0; r < 4; ++r) s[r] += __shfl_xor(s[r], m, 64);
    }
    if (ln == 0) {
#pragma unroll
        for (int r = 0; r < 4; ++r) part[wave][quad * 4 + r] = s[r];
    }
    __syncthreads();
    if (tx < 16) {
        float t = part[0][tx] + part[1][tx] + part[2][tx] + part[3][tx];
        scl[tx] = 1.f / fmaxf(sqrtf(t), 1e-12f);
    }
    __syncthreads();
#pragma unroll
    for (int r = 0; r < 4; ++r) {
        const int row = quad * 4 + r;
        const float sc = scl[row];
        float o0 = fmaxf(v0[r] * sc, 0.f) + bf2f(At[row * 264 + 128 + n0 + ln]);
        float o1 = fmaxf(v1[r] * sc, 0.f) + bf2f(At[row * 264 + 128 + n0 + 16 + ln]);
        out[(size_t)(rowbase + row) * H + n0 + ln] = f2bf(o0);
        out[(size_t)(rowbase + row) * H + n0 + 16 + ln] = f2bf(o1);
    }
}

// ---------------------------------------------------------------------------
// head (MFMA GEMM1 + small fp32 GEMM2):
//   z = relu(hu @ w1 + b1); out = z @ w2 + b2
// ---------------------------------------------------------------------------
__global__ void head_kernel(const ushortT* __restrict__ hu, const ushortT* __restrict__ w1T,
                            const float* __restrict__ b1, const float* __restrict__ w2,
                            const float* __restrict__ b2, float* __restrict__ out) {
    __shared__ ushortT hs[16 * 136];
    __shared__ float zs[16 * 72];
    const int tx = threadIdx.x;
    const int rowbase = blockIdx.x * 16;
    {
        int r = tx >> 4, ch = tx & 15;
        *reinterpret_cast<short8*>(&hs[r * 136 + ch * 8]) =
            *reinterpret_cast<const short8*>(&hu[(size_t)(rowbase + r) * H + ch * 8]);
    }
    __syncthreads();
    const int wave = tx >> 6, lane = tx & 63;
    const int ln = lane & 15, quad = lane >> 4;
    floatx4 acc = {0.f, 0.f, 0.f, 0.f};
#pragma unroll
    for (int k0 = 0; k0 < 128; k0 += 32) {
        short8 af = *reinterpret_cast<const short8*>(&hs[ln * 136 + k0 + quad * 8]);
        short8 bf = *reinterpret_cast<const short8*>(&w1T[(wave * 16 + ln) * 128 + k0 + quad * 8]);
        acc = __builtin_amdgcn_mfma_f32_16x16x32_bf16(af, bf, acc, 0, 0, 0);
    }
    const float bv = b1[wave * 16 + ln];
#pragma unroll
    for (int r = 0; r < 4; ++r)
        zs[(quad * 4 + r) * 72 + wave * 16 + ln] = fmaxf(acc[r] + bv, 0.f);
    __syncthreads();
    if (tx < 128) {
        int r = tx >> 3, c = tx & 7;
        float a = b2[c];
#pragma unroll 8
        for (int k = 0; k < 64; ++k) a += zs[r * 72 + k] * w2[k * 8 + c];
        out[(size_t)(rowbase + r) * 8 + c] = a;
    }
}

// ---------------------------------------------------------------------------
extern "C" void kernel_launch(void* const* d_in, const int* in_sizes, int n_in,
                              void* d_out, int out_size, void* d_ws, size_t ws_size,
                              hipStream_t stream) {
    const float* x_user     = (const float*)d_in[0];
    const float* x_item     = (const float*)d_in[1];
    const int*   ei_u2i     = (const int*)d_in[2];
    const int*   ei_i2u     = (const int*)d_in[3];
    const float* enc_user_w = (const float*)d_in[4];
    const float* enc_user_b = (const float*)d_in[5];
    const float* enc_item_w = (const float*)d_in[6];
    const float* enc_item_b = (const float*)d_in[7];
    const float* W[12];
    for (int i = 0; i < 12; ++i) W[i] = (const float*)d_in[8 + i];
    const float* head_w1 = (const float*)d_in[20];
    const float* head_b1 = (const float*)d_in[21];
    const float* head_w2 = (const float*)d_in[22];
    const float* head_b2 = (const float*)d_in[23];
    float* out = (float*)d_out;

    const size_t S = (size_t)NNODE * H;
    ushortT* huA  = (ushortT*)d_ws;
    ushortT* huB  = huA + S;
    ushortT* hiA  = huB + S;
    ushortT* hiB  = hiA + S;
    ushortT* wT   = hiB + S;                  // 151552 bf16
    int*   cnt_i  = (int*)(wT + 151552);
    int*   cnt_u  = cnt_i + NNODE;            // adjacent to cnt_i (single memset)
    int*   off_i  = cnt_u + NNODE;
    int*   off_u  = off_i + NNODE;
    int*   cur_i  = off_u + NNODE;
    int*   cur_u  = cur_i + NNODE;
    int*   bsum_i = cur_u + NNODE;
    int*   bsum_u = bsum_i + 64;
    int*   src_u2i = bsum_u + 64;             // [NEDGE]
    int*   src_i2u = src_u2i + NEDGE;         // [NEDGE]

    const ushortT* wTeu = wT + 131072;
    const ushortT* wTei = wT + 139264;
    const ushortT* w1T  = wT + 143360;

    // all weight converts in one dispatch (order: l0 wl_ui, wr_ui, wl_iu, wr_iu; l1 same)
    convert_all_kernel<<<592, 256, 0, stream>>>(
        W[0], W[2], W[3], W[5], W[6], W[8], W[9], W[11],
        enc_user_w, enc_item_w, head_w1, wT);

    // both encoders, one dispatch
    encode2_kernel<<<2 * NBLK16, 256, 0, stream>>>(
        x_user, wTeu, enc_user_b, x_item, wTei, enc_item_b, huA, hiA);

    // CSR build (shared by both layers)
    hipMemsetAsync(cnt_i, 0, 2 * NNODE * sizeof(int), stream);
    count2_kernel<<<(2 * NEDGE) / 256, 256, 0, stream>>>(ei_u2i + NEDGE, ei_i2u + NEDGE, cnt_i, cnt_u, NEDGE);
    scan1_kernel<<<2 * NB, 256, 0, stream>>>(cnt_i, off_i, bsum_i, cnt_u, off_u, bsum_u, NNODE);
    scan2_kernel<<<1, 64, 0, stream>>>(bsum_i, bsum_u, NB);
    const int nb3 = (NNODE + 255) / 256;      // 196
    scan3_kernel<<<2 * nb3, 256, 0, stream>>>(off_i, cur_i, bsum_i, off_u, cur_u, bsum_u, nb3, NNODE);
    fill2_kernel<<<(2 * NEDGE) / 256, 256, 0, stream>>>(ei_u2i, ei_i2u, cur_i, cur_u, src_u2i, src_i2u, NEDGE);

    // layer 0: new_hi=f(huA,hiA)->hiB ; new_hu=f(hiA,huA)->huB   (one dispatch)
    sage2_kernel<<<2 * NBLK16, 256, 0, stream>>>(
        huA, src_u2i, off_i, cnt_i, hiA, wT + 0 * 16384, W[1], wT + 1 * 16384, hiB,
        hiA, src_i2u, off_u, cnt_u, huA, wT + 2 * 16384, W[4], wT + 3 * 16384, huB);

    // layer 1: new_hi=f(huB,hiB)->hiA ; new_hu=f(hiB,huB)->huA
    sage2_kernel<<<2 * NBLK16, 256, 0, stream>>>(
        huB, src_u2i, off_i, cnt_i, hiB, wT + 4 * 16384, W[7], wT + 5 * 16384, hiA,
        hiB, src_i2u, off_u, cnt_u, huB, wT + 6 * 16384, W[10], wT + 7 * 16384, huA);

    head_kernel<<<NBLK16, 256, 0, stream>>>(huA, w1T, head_b1, head_w2, head_b2, out);
}

// Round 5
// 384.280 us; speedup vs baseline: 5.2825x; 1.4598x over previous
//
#include <hip/hip_runtime.h>
#include <math.h>

#define H 128
#define NNODE 50000
#define NEDGE 800000
#define NBLK16 3125      // NNODE / 16
#define NB 49            // scan blocks per array (1024 elems each)
#define NBUK 782         // buckets of 64 dst nodes: ceil(50000/64)
#define BCH 64           // edge chunks per type
#define CHUNK 12500      // NEDGE / BCH
#define SCANH_N 50048    // NBUK * 64
#define BCAP 1536        // max edges per bucket (mean 1024, sigma 32)

typedef unsigned short ushortT;
typedef unsigned int uintT;
typedef __attribute__((ext_vector_type(8))) short short8;
typedef __attribute__((ext_vector_type(4))) float floatx4;

static __device__ __forceinline__ float bf2f(ushortT u) {
    union { uintT i; float f; } c; c.i = ((uintT)u) << 16; return c.f;
}
static __device__ __forceinline__ ushortT f2bf(float f) {
    union { float f; uintT i; } c; c.f = f;
    uintT lsb = (c.i >> 16) & 1;
    c.i += 0x7fffu + lsb;          // round-to-nearest-even
    return (ushortT)(c.i >> 16);
}
static __device__ __forceinline__ float lo2f(uintT v) {
    union { uintT i; float f; } c; c.i = v << 16; return c.f;
}
static __device__ __forceinline__ float hi2f(uintT v) {
    union { uintT i; float f; } c; c.i = v & 0xffff0000u; return c.f;
}
static __device__ __forceinline__ uintT pack2(float a, float b) {
    return (uintT)f2bf(a) | ((uintT)f2bf(b) << 16);
}

// ---------------------------------------------------------------------------
// one-shot weight convert+transpose for all matrices (bf16, [col][k] k-contig)
// ---------------------------------------------------------------------------
__global__ void convert_all_kernel(const float* __restrict__ s0, const float* __restrict__ s1,
                                   const float* __restrict__ s2, const float* __restrict__ s3,
                                   const float* __restrict__ s4, const float* __restrict__ s5,
                                   const float* __restrict__ s6, const float* __restrict__ s7,
                                   const float* __restrict__ seu, const float* __restrict__ sei,
                                   const float* __restrict__ sw1, ushortT* __restrict__ wT) {
    const int b = blockIdx.x, t = threadIdx.x;
    if (b < 512) {
        const int m = b >> 6;
        const float* s = (m == 0) ? s0 : (m == 1) ? s1 : (m == 2) ? s2 : (m == 3) ? s3
                       : (m == 4) ? s4 : (m == 5) ? s5 : (m == 6) ? s6 : s7;
        int i = (b & 63) * 256 + t;
        int k = i >> 7, c = i & 127;
        wT[m * 16384 + c * 128 + k] = f2bf(s[k * 128 + c]);
    } else if (b < 544) {
        int i = (b - 512) * 256 + t;          // 8192
        int k = i >> 7, c = i & 127;
        wT[131072 + c * 64 + k] = f2bf(seu[k * 128 + c]);
    } else if (b < 560) {
        int i = (b - 544) * 256 + t;          // 4096
        int k = i >> 7, c = i & 127;
        wT[139264 + c * 32 + k] = f2bf(sei[k * 128 + c]);
    } else {
        int i = (b - 560) * 256 + t;          // 8192
        int k = i >> 6, c = i & 63;
        wT[143360 + c * 128 + k] = f2bf(sw1[k * 64 + c]);
    }
}

// ---------------------------------------------------------------------------
// merged encoders (MFMA): blocks [0,3125) user K=64, [3125,6250) item K=32
// ---------------------------------------------------------------------------
__global__ void encode2_kernel(const float* __restrict__ xu, const ushortT* __restrict__ wTu,
                               const float* __restrict__ bu,
                               const float* __restrict__ xi, const ushortT* __restrict__ wTi,
                               const float* __restrict__ bi,
                               ushortT* __restrict__ outu, ushortT* __restrict__ outi) {
    __shared__ ushortT xs[16 * 72];
    const bool user = blockIdx.x < NBLK16;
    const int blk = user ? blockIdx.x : blockIdx.x - NBLK16;
    const int K = user ? 64 : 32;
    const int kshift = user ? 6 : 5;
    const int stride = K + 8;
    const float* x = user ? xu : xi;
    const ushortT* wT = user ? wTu : wTi;
    const float* bias = user ? bu : bi;
    ushortT* out = user ? outu : outi;

    const int tx = threadIdx.x;
    const int rowbase = blk * 16;

    {
        int i = tx * 4;
        if (i < 16 * K) {
            const float4 v = *reinterpret_cast<const float4*>(&x[(size_t)rowbase * K + i]);
            int r = i >> kshift, c = i & (K - 1);
            uint2 w;
            w.x = pack2(v.x, v.y);
            w.y = pack2(v.z, v.w);
            *reinterpret_cast<uint2*>(&xs[r * stride + c]) = w;
        }
    }
    __syncthreads();

    const int wave = tx >> 6, lane = tx & 63;
    const int ln = lane & 15, quad = lane >> 4;
    const int n0 = wave * 32;
    floatx4 acc0 = {0.f, 0.f, 0.f, 0.f};
    floatx4 acc1 = {0.f, 0.f, 0.f, 0.f};
    for (int k0 = 0; k0 < K; k0 += 32) {
        short8 af = *reinterpret_cast<const short8*>(&xs[ln * stride + k0 + quad * 8]);
        short8 b0 = *reinterpret_cast<const short8*>(&wT[(n0 + ln) * K + k0 + quad * 8]);
        short8 b1 = *reinterpret_cast<const short8*>(&wT[(n0 + 16 + ln) * K + k0 + quad * 8]);
        acc0 = __builtin_amdgcn_mfma_f32_16x16x32_bf16(af, b0, acc0, 0, 0, 0);
        acc1 = __builtin_amdgcn_mfma_f32_16x16x32_bf16(af, b1, acc1, 0, 0, 0);
    }
    const float b0v = bias[n0 + ln], b1v = bias[n0 + 16 + ln];
#pragma unroll
    for (int r = 0; r < 4; ++r) {
        int row = rowbase + quad * 4 + r;
        out[(size_t)row * H + n0 + ln] = f2bf(fmaxf(acc0[r] + b0v, 0.f));
        out[(size_t)row * H + n0 + 16 + ln] = f2bf(fmaxf(acc1[r] + b1v, 0.f));
    }
}

// ---------------------------------------------------------------------------
// CSR build, pass 1: per-(chunk,bucket) histogram. 128 blocks: [0,64) type0.
// scanH layout: [bucket][chunk] flattened -> index b*64 + c.
// ---------------------------------------------------------------------------
__global__ void histA_kernel(const int* __restrict__ e0, const int* __restrict__ e1,
                             int* __restrict__ scanH0, int* __restrict__ scanH1) {
    __shared__ int hist[NBUK];
    const int tx = threadIdx.x;
    const bool first = blockIdx.x < BCH;
    const int c = first ? blockIdx.x : blockIdx.x - BCH;
    const int* edst = (first ? e0 : e1) + NEDGE + c * CHUNK;
    int* scanH = first ? scanH0 : scanH1;

    for (int i = tx; i < NBUK; i += 256) hist[i] = 0;
    __syncthreads();
    for (int e = tx; e < CHUNK; e += 256) atomicAdd(&hist[edst[e] >> 6], 1);
    __syncthreads();
    for (int i = tx; i < NBUK; i += 256) scanH[i * BCH + c] = hist[i];
}

// ---------------------------------------------------------------------------
// exclusive scan over SCANH_N elems, in-place (off==cnt is safe), two arrays
// ---------------------------------------------------------------------------
__global__ void scan1_kernel(const int* __restrict__ cnt1, int* __restrict__ off1, int* __restrict__ bsum1,
                             const int* __restrict__ cnt2, int* __restrict__ off2, int* __restrict__ bsum2,
                             int N) {
    __shared__ int tmp[256];
    const bool first = blockIdx.x < NB;
    const int blk = first ? blockIdx.x : blockIdx.x - NB;
    const int* cnt = first ? cnt1 : cnt2;
    int* off = first ? off1 : off2;
    int* bsum = first ? bsum1 : bsum2;
    const int tx = threadIdx.x;
    const int base = blk * 1024;
    int v[4];
    int s = 0;
#pragma unroll
    for (int k = 0; k < 4; ++k) {
        int i = base + tx * 4 + k;
        v[k] = (i < N) ? cnt[i] : 0;
        s += v[k];
    }
    tmp[tx] = s;
    __syncthreads();
    for (int o = 1; o < 256; o <<= 1) {
        int t = (tx >= o) ? tmp[tx - o] : 0;
        __syncthreads();
        tmp[tx] += t;
        __syncthreads();
    }
    int excl = (tx == 0) ? 0 : tmp[tx - 1];
#pragma unroll
    for (int k = 0; k < 4; ++k) {
        int i = base + tx * 4 + k;
        if (i < N) off[i] = excl;
        excl += v[k];
    }
    if (tx == 255) bsum[blk] = tmp[255];
}

__global__ void scan2_kernel(int* __restrict__ b1, int* __restrict__ b2, int nb) {
    if (threadIdx.x < 2) {
        int* b = (threadIdx.x == 0) ? b1 : b2;
        int s = 0;
        for (int i = 0; i < nb; ++i) { int v = b[i]; b[i] = s; s += v; }
    }
}

// ---------------------------------------------------------------------------
// CSR build, pass 2: scatter packed (dst<<16 | src) into per-(bucket,chunk)
// exclusive sub-ranges -> ~1 full line per (bucket,chunk), no global atomics.
// ---------------------------------------------------------------------------
__global__ void scatterA_kernel(const int* __restrict__ e0, const int* __restrict__ e1,
                                const int* __restrict__ scanH0, const int* __restrict__ bsum0,
                                const int* __restrict__ scanH1, const int* __restrict__ bsum1,
                                uintT* __restrict__ stage0, uintT* __restrict__ stage1) {
    __shared__ int cur[NBUK];
    const int tx = threadIdx.x;
    const bool first = blockIdx.x < BCH;
    const int c = first ? blockIdx.x : blockIdx.x - BCH;
    const int* ei = first ? e0 : e1;
    const int* scanH = first ? scanH0 : scanH1;
    const int* bsum = first ? bsum0 : bsum1;
    uintT* stage = first ? stage0 : stage1;

    for (int i = tx; i < NBUK; i += 256) {
        int idx = i * BCH + c;
        cur[i] = scanH[idx] + bsum[idx >> 10];
    }
    __syncthreads();
    const int base = c * CHUNK;
    for (int e = tx; e < CHUNK; e += 256) {
        int s = ei[base + e];
        int d = ei[NEDGE + base + e];
        int pos = atomicAdd(&cur[d >> 6], 1);
        stage[pos] = ((uintT)d << 16) | (uintT)s;
    }
}

// ---------------------------------------------------------------------------
// CSR build, pass 3: per-bucket local sort by dst; dense u16 srcidx dump +
// off[] write. One block per bucket; blocks [0,NBUK) type0.
// ---------------------------------------------------------------------------
__global__ void passB_kernel(const uintT* __restrict__ stage0, const int* __restrict__ scanH0,
                             const int* __restrict__ bsum0, ushortT* __restrict__ srcidx0,
                             int* __restrict__ off0,
                             const uintT* __restrict__ stage1, const int* __restrict__ scanH1,
                             const int* __restrict__ bsum1, ushortT* __restrict__ srcidx1,
                             int* __restrict__ off1) {
    __shared__ uintT inbuf[BCAP];
    __shared__ ushortT outbuf[BCAP];
    __shared__ int hist[64], scn[64], cur[64];
    const int tx = threadIdx.x;
    const bool first = blockIdx.x < NBUK;
    const int b = first ? blockIdx.x : blockIdx.x - NBUK;
    const uintT* stage = first ? stage0 : stage1;
    const int* scanH = first ? scanH0 : scanH1;
    const int* bsum = first ? bsum0 : bsum1;
    ushortT* srcidx = first ? srcidx0 : srcidx1;
    int* off = first ? off0 : off1;

    const int ib = b * BCH;                       // == b*64, index of [b][0]
    const int base = scanH[ib] + bsum[ib >> 10];
    const int end = (b == NBUK - 1) ? NEDGE : (scanH[ib + BCH] + bsum[(ib + BCH) >> 10]);
    const int size = end - base;

    if (tx < 64) hist[tx] = 0;
    for (int i = tx; i < size; i += 256) inbuf[i] = stage[base + i];
    __syncthreads();
    for (int i = tx; i < size; i += 256) atomicAdd(&hist[(inbuf[i] >> 16) & 63], 1);
    __syncthreads();
    if (tx == 0) {
        int s = 0;
#pragma unroll
        for (int i = 0; i < 64; ++i) { scn[i] = s; s += hist[i]; }
    }
    __syncthreads();
    if (tx < 64) cur[tx] = scn[tx];
    __syncthreads();
    for (int i = tx; i < size; i += 256) {
        uintT w = inbuf[i];
        int pos = atomicAdd(&cur[(w >> 16) & 63], 1);
        outbuf[pos] = (ushortT)(w & 0xffffu);
    }
    __syncthreads();
    for (int i = tx; i < size; i += 256) srcidx[base + i] = outbuf[i];
    if (tx < 64) {
        int d = b * 64 + tx;
        if (d < NNODE) off[d] = base + scn[tx];
    }
    if (b == NBUK - 1 && tx == 64) off[NNODE] = NEDGE;
}

// ---------------------------------------------------------------------------
// merged SAGE pair (one hetero layer, both directions) — fused gather + MFMA
//   out = relu( l2norm( [mean_gather(xsrc) | xdst] @ [wl;wr] + bl ) ) + xdst
// ---------------------------------------------------------------------------
__global__ void sage2_kernel(
    const ushortT* __restrict__ xsrcA, const ushortT* __restrict__ srcA,
    const int* __restrict__ offA,
    const ushortT* __restrict__ xdstA, const ushortT* __restrict__ wlTA,
    const float* __restrict__ blA, const ushortT* __restrict__ wrTA, ushortT* __restrict__ outA,
    const ushortT* __restrict__ xsrcB, const ushortT* __restrict__ srcB,
    const int* __restrict__ offB,
    const ushortT* __restrict__ xdstB, const ushortT* __restrict__ wlTB,
    const float* __restrict__ blB, const ushortT* __restrict__ wrTB, ushortT* __restrict__ outB) {
    __shared__ ushortT At[16 * 264];
    __shared__ float part[4][16];
    __shared__ float scl[16];
    const bool first = blockIdx.x < NBLK16;
    const int blk = first ? blockIdx.x : blockIdx.x - NBLK16;
    const ushortT* xsrc = first ? xsrcA : xsrcB;
    const ushortT* srcidx = first ? srcA : srcB;
    const int* off      = first ? offA  : offB;
    const ushortT* xdst = first ? xdstA : xdstB;
    const ushortT* wlT  = first ? wlTA  : wlTB;
    const float* bl     = first ? blA   : blB;
    const ushortT* wrT  = first ? wrTA  : wrTB;
    ushortT* out        = first ? outA  : outB;

    const int tx = threadIdx.x;
    const int rowbase = blk * 16;
    const int wave = tx >> 6, lane = tx & 63;

    {   // stage xdst tile into k-slots 128..255
        int r = tx >> 4, ch = tx & 15;
        *reinterpret_cast<short8*>(&At[r * 264 + 128 + ch * 8]) =
            *reinterpret_cast<const short8*>(&xdst[(size_t)(rowbase + r) * H + ch * 8]);
    }

    // gather-mean, 4 rows per wave, masked unroll-8 for MLP
    const uintT* src32 = (const uintT*)xsrc;
#pragma unroll
    for (int rr = 0; rr < 4; ++rr) {
        const int r = wave * 4 + rr;
        const int row = rowbase + r;
        const int start = off[row];
        const int deg = off[row + 1] - start;
        const ushortT* sidx = srcidx + start;
        float a0 = 0.f, a1 = 0.f;
        int j = 0;
        for (; j + 8 <= deg; j += 8) {
            int ii[8];
            uintT vv[8];
#pragma unroll
            for (int k = 0; k < 8; ++k) ii[k] = sidx[j + k];
#pragma unroll
            for (int k = 0; k < 8; ++k) vv[k] = src32[(size_t)ii[k] * 64 + lane];
#pragma unroll
            for (int k = 0; k < 8; ++k) { a0 += lo2f(vv[k]); a1 += hi2f(vv[k]); }
        }
        if (j < deg) {
            const int rem = deg - j;           // 1..7, wave-uniform
            int ii[8];
            uintT vv[8];
#pragma unroll
            for (int k = 0; k < 8; ++k) ii[k] = sidx[j + (k < rem ? k : rem - 1)];
#pragma unroll
            for (int k = 0; k < 8; ++k) vv[k] = src32[(size_t)ii[k] * 64 + lane];
#pragma unroll
            for (int k = 0; k < 8; ++k) {
                float m = (k < rem) ? 1.f : 0.f;
                a0 += lo2f(vv[k]) * m;
                a1 += hi2f(vv[k]) * m;
            }
        }
        float inv = 1.f / fmaxf((float)deg, 1.f);
        *reinterpret_cast<uintT*>(&At[r * 264 + lane * 2]) = pack2(a0 * inv, a1 * inv);
    }
    __syncthreads();

    // MFMA: wave w -> cols [32w, 32w+32)
    const int ln = lane & 15, quad = lane >> 4;
    const int n0 = wave * 32;
    floatx4 acc0 = {0.f, 0.f, 0.f, 0.f};
    floatx4 acc1 = {0.f, 0.f, 0.f, 0.f};
#pragma unroll
    for (int k0 = 0; k0 < 256; k0 += 32) {
        short8 af = *reinterpret_cast<const short8*>(&At[ln * 264 + k0 + quad * 8]);
        const ushortT* wT = (k0 < 128) ? wlT : wrT;
        const int kk = (k0 & 127) + quad * 8;
        short8 b0 = *reinterpret_cast<const short8*>(&wT[(n0 + ln) * 128 + kk]);
        short8 b1 = *reinterpret_cast<const short8*>(&wT[(n0 + 16 + ln) * 128 + kk]);
        acc0 = __builtin_amdgcn_mfma_f32_16x16x32_bf16(af, b0, acc0, 0, 0, 0);
        acc1 = __builtin_amdgcn_mfma_f32_16x16x32_bf16(af, b1, acc1, 0, 0, 0);
    }

    // epilogue: bias, row L2-norm, relu, residual(+xdst), bf16 store
    const float bl0 = bl[n0 + ln];
    const float bl1 = bl[n0 + 16 + ln];
    float v0[4], v1[4], s[4];
#pragma unroll
    for (int r = 0; r < 4; ++r) {
        v0[r] = acc0[r] + bl0;
        v1[r] = acc1[r] + bl1;
        s[r] = v0[r] * v0[r] + v1[r] * v1[r];
    }
#pragma unroll
    for (int m = 1; m < 16; m <<= 1) {
#pragma unroll
        for (int r = 0; r < 4; ++r) s[r] += __shfl_xor(s[r], m, 64);
    }
    if (ln == 0) {
#pragma unroll
        for (int r = 0; r < 4; ++r) part[wave][quad * 4 + r] = s[r];
    }
    __syncthreads();
    if (tx < 16) {
        float t = part[0][tx] + part[1][tx] + part[2][tx] + part[3][tx];
        scl[tx] = 1.f / fmaxf(sqrtf(t), 1e-12f);
    }
    __syncthreads();
#pragma unroll
    for (int r = 0; r < 4; ++r) {
        const int row = quad * 4 + r;
        const float sc = scl[row];
        float o0 = fmaxf(v0[r] * sc, 0.f) + bf2f(At[row * 264 + 128 + n0 + ln]);
        float o1 = fmaxf(v1[r] * sc, 0.f) + bf2f(At[row * 264 + 128 + n0 + 16 + ln]);
        out[(size_t)(rowbase + row) * H + n0 + ln] = f2bf(o0);
        out[(size_t)(rowbase + row) * H + n0 + 16 + ln] = f2bf(o1);
    }
}

// ---------------------------------------------------------------------------
// head (MFMA GEMM1 + small fp32 GEMM2)
// ---------------------------------------------------------------------------
__global__ void head_kernel(const ushortT* __restrict__ hu, const ushortT* __restrict__ w1T,
                            const float* __restrict__ b1, const float* __restrict__ w2,
                            const float* __restrict__ b2, float* __restrict__ out) {
    __shared__ ushortT hs[16 * 136];
    __shared__ float zs[16 * 72];
    const int tx = threadIdx.x;
    const int rowbase = blockIdx.x * 16;
    {
        int r = tx >> 4, ch = tx & 15;
        *reinterpret_cast<short8*>(&hs[r * 136 + ch * 8]) =
            *reinterpret_cast<const short8*>(&hu[(size_t)(rowbase + r) * H + ch * 8]);
    }
    __syncthreads();
    const int wave = tx >> 6, lane = tx & 63;
    const int ln = lane & 15, quad = lane >> 4;
    floatx4 acc = {0.f, 0.f, 0.f, 0.f};
#pragma unroll
    for (int k0 = 0; k0 < 128; k0 += 32) {
        short8 af = *reinterpret_cast<const short8*>(&hs[ln * 136 + k0 + quad * 8]);
        short8 bf = *reinterpret_cast<const short8*>(&w1T[(wave * 16 + ln) * 128 + k0 + quad * 8]);
        acc = __builtin_amdgcn_mfma_f32_16x16x32_bf16(af, bf, acc, 0, 0, 0);
    }
    const float bv = b1[wave * 16 + ln];
#pragma unroll
    for (int r = 0; r < 4; ++r)
        zs[(quad * 4 + r) * 72 + wave * 16 + ln] = fmaxf(acc[r] + bv, 0.f);
    __syncthreads();
    if (tx < 128) {
        int r = tx >> 3, c = tx & 7;
        float a = b2[c];
#pragma unroll 8
        for (int k = 0; k < 64; ++k) a += zs[r * 72 + k] * w2[k * 8 + c];
        out[(size_t)(rowbase + r) * 8 + c] = a;
    }
}

// ---------------------------------------------------------------------------
extern "C" void kernel_launch(void* const* d_in, const int* in_sizes, int n_in,
                              void* d_out, int out_size, void* d_ws, size_t ws_size,
                              hipStream_t stream) {
    const float* x_user     = (const float*)d_in[0];
    const float* x_item     = (const float*)d_in[1];
    const int*   ei_u2i     = (const int*)d_in[2];
    const int*   ei_i2u     = (const int*)d_in[3];
    const float* enc_user_w = (const float*)d_in[4];
    const float* enc_user_b = (const float*)d_in[5];
    const float* enc_item_w = (const float*)d_in[6];
    const float* enc_item_b = (const float*)d_in[7];
    const float* W[12];
    for (int i = 0; i < 12; ++i) W[i] = (const float*)d_in[8 + i];
    const float* head_w1 = (const float*)d_in[20];
    const float* head_b1 = (const float*)d_in[21];
    const float* head_w2 = (const float*)d_in[22];
    const float* head_b2 = (const float*)d_in[23];
    float* out = (float*)d_out;

    const size_t S = (size_t)NNODE * H;
    ushortT* huA  = (ushortT*)d_ws;
    ushortT* huB  = huA + S;
    ushortT* hiA  = huB + S;
    ushortT* hiB  = hiA + S;
    ushortT* wT   = hiB + S;                  // 151552 bf16
    int*    scanH_i = (int*)(wT + 151552);    // [SCANH_N]
    int*    scanH_u = scanH_i + SCANH_N;
    int*    bsum_i  = scanH_u + SCANH_N;      // [64]
    int*    bsum_u  = bsum_i + 64;
    int*    off_i   = bsum_u + 64;            // [NNODE+1]
    int*    off_u   = off_i + NNODE + 1;
    uintT*  stage_i = (uintT*)(off_u + NNODE + 1);  // [NEDGE]
    uintT*  stage_u = stage_i + NEDGE;
    ushortT* src_i  = (ushortT*)(stage_u + NEDGE);  // [NEDGE] u16
    ushortT* src_u  = src_i + NEDGE;

    const ushortT* wTeu = wT + 131072;
    const ushortT* wTei = wT + 139264;
    const ushortT* w1T  = wT + 143360;

    convert_all_kernel<<<592, 256, 0, stream>>>(
        W[0], W[2], W[3], W[5], W[6], W[8], W[9], W[11],
        enc_user_w, enc_item_w, head_w1, wT);

    encode2_kernel<<<2 * NBLK16, 256, 0, stream>>>(
        x_user, wTeu, enc_user_b, x_item, wTei, enc_item_b, huA, hiA);

    // CSR build: hist -> scan -> locality-preserving scatter -> local sort
    histA_kernel<<<2 * BCH, 256, 0, stream>>>(ei_u2i, ei_i2u, scanH_i, scanH_u);
    scan1_kernel<<<2 * NB, 256, 0, stream>>>(scanH_i, scanH_i, bsum_i,
                                             scanH_u, scanH_u, bsum_u, SCANH_N);
    scan2_kernel<<<1, 64, 0, stream>>>(bsum_i, bsum_u, NB);
    scatterA_kernel<<<2 * BCH, 256, 0, stream>>>(ei_u2i, ei_i2u, scanH_i, bsum_i,
                                                 scanH_u, bsum_u, stage_i, stage_u);
    passB_kernel<<<2 * NBUK, 256, 0, stream>>>(stage_i, scanH_i, bsum_i, src_i, off_i,
                                               stage_u, scanH_u, bsum_u, src_u, off_u);

    // layer 0: new_hi=f(huA,hiA)->hiB ; new_hu=f(hiA,huA)->huB
    sage2_kernel<<<2 * NBLK16, 256, 0, stream>>>(
        huA, src_i, off_i, hiA, wT + 0 * 16384, W[1], wT + 1 * 16384, hiB,
        hiA, src_u, off_u, huA, wT + 2 * 16384, W[4], wT + 3 * 16384, huB);

    // layer 1: new_hi=f(huB,hiB)->hiA ; new_hu=f(hiB,huB)->huA
    sage2_kernel<<<2 * NBLK16, 256, 0, stream>>>(
        huB, src_i, off_i, hiB, wT + 4 * 16384, W[7], wT + 5 * 16384, hiA,
        hiB, src_u, off_u, huB, wT + 6 * 16384, W[10], wT + 7 * 16384, huA);

    head_kernel<<<NBLK16, 256, 0, stream>>>(huA, w1T, head_b1, head_w2, head_b2, out);
}

// Round 6
// 382.913 us; speedup vs baseline: 5.3013x; 1.0036x over previous
//
#include <hip/hip_runtime.h>
#include <math.h>

#define H 128
#define NNODE 50000
#define NEDGE 800000
#define NBLK16 3125      // NNODE / 16
#define NB 49            // scan blocks per array (1024 elems each)
#define NBUK 782         // buckets of 64 dst nodes: ceil(50000/64)
#define BCH 64           // edge chunks per type
#define CHUNK 12500      // NEDGE / BCH
#define SCANH_N 50048    // NBUK * 64
#define BCAP 1536        // max edges per bucket (mean 1024)
#define IDXCAP 2048      // staged srcidx per 16-row block (mean 256)

typedef unsigned short ushortT;
typedef unsigned int uintT;
typedef __attribute__((ext_vector_type(8))) short short8;
typedef __attribute__((ext_vector_type(4))) float floatx4;

static __device__ __forceinline__ float bf2f(ushortT u) {
    union { uintT i; float f; } c; c.i = ((uintT)u) << 16; return c.f;
}
static __device__ __forceinline__ ushortT f2bf(float f) {
    union { float f; uintT i; } c; c.f = f;
    uintT lsb = (c.i >> 16) & 1;
    c.i += 0x7fffu + lsb;          // round-to-nearest-even
    return (ushortT)(c.i >> 16);
}
static __device__ __forceinline__ float lo2f(uintT v) {
    union { uintT i; float f; } c; c.i = v << 16; return c.f;
}
static __device__ __forceinline__ float hi2f(uintT v) {
    union { uintT i; float f; } c; c.i = v & 0xffff0000u; return c.f;
}
static __device__ __forceinline__ uintT pack2(float a, float b) {
    return (uintT)f2bf(a) | ((uintT)f2bf(b) << 16);
}

// ---------------------------------------------------------------------------
// one-shot weight convert+transpose for all matrices (bf16, [col][k] k-contig)
// ---------------------------------------------------------------------------
__global__ void convert_all_kernel(const float* __restrict__ s0, const float* __restrict__ s1,
                                   const float* __restrict__ s2, const float* __restrict__ s3,
                                   const float* __restrict__ s4, const float* __restrict__ s5,
                                   const float* __restrict__ s6, const float* __restrict__ s7,
                                   const float* __restrict__ seu, const float* __restrict__ sei,
                                   const float* __restrict__ sw1, ushortT* __restrict__ wT) {
    const int b = blockIdx.x, t = threadIdx.x;
    if (b < 512) {
        const int m = b >> 6;
        const float* s = (m == 0) ? s0 : (m == 1) ? s1 : (m == 2) ? s2 : (m == 3) ? s3
                       : (m == 4) ? s4 : (m == 5) ? s5 : (m == 6) ? s6 : s7;
        int i = (b & 63) * 256 + t;
        int k = i >> 7, c = i & 127;
        wT[m * 16384 + c * 128 + k] = f2bf(s[k * 128 + c]);
    } else if (b < 544) {
        int i = (b - 512) * 256 + t;          // 8192
        int k = i >> 7, c = i & 127;
        wT[131072 + c * 64 + k] = f2bf(seu[k * 128 + c]);
    } else if (b < 560) {
        int i = (b - 544) * 256 + t;          // 4096
        int k = i >> 7, c = i & 127;
        wT[139264 + c * 32 + k] = f2bf(sei[k * 128 + c]);
    } else {
        int i = (b - 560) * 256 + t;          // 8192
        int k = i >> 6, c = i & 63;
        wT[143360 + c * 128 + k] = f2bf(sw1[k * 64 + c]);
    }
}

// ---------------------------------------------------------------------------
// merged encoders (MFMA): blocks [0,3125) user K=64, [3125,6250) item K=32
// ---------------------------------------------------------------------------
__global__ void encode2_kernel(const float* __restrict__ xu, const ushortT* __restrict__ wTu,
                               const float* __restrict__ bu,
                               const float* __restrict__ xi, const ushortT* __restrict__ wTi,
                               const float* __restrict__ bi,
                               ushortT* __restrict__ outu, ushortT* __restrict__ outi) {
    __shared__ ushortT xs[16 * 72];
    const bool user = blockIdx.x < NBLK16;
    const int blk = user ? blockIdx.x : blockIdx.x - NBLK16;
    const int K = user ? 64 : 32;
    const int kshift = user ? 6 : 5;
    const int stride = K + 8;
    const float* x = user ? xu : xi;
    const ushortT* wT = user ? wTu : wTi;
    const float* bias = user ? bu : bi;
    ushortT* out = user ? outu : outi;

    const int tx = threadIdx.x;
    const int rowbase = blk * 16;

    {
        int i = tx * 4;
        if (i < 16 * K) {
            const float4 v = *reinterpret_cast<const float4*>(&x[(size_t)rowbase * K + i]);
            int r = i >> kshift, c = i & (K - 1);
            uint2 w;
            w.x = pack2(v.x, v.y);
            w.y = pack2(v.z, v.w);
            *reinterpret_cast<uint2*>(&xs[r * stride + c]) = w;
        }
    }
    __syncthreads();

    const int wave = tx >> 6, lane = tx & 63;
    const int ln = lane & 15, quad = lane >> 4;
    const int n0 = wave * 32;
    floatx4 acc0 = {0.f, 0.f, 0.f, 0.f};
    floatx4 acc1 = {0.f, 0.f, 0.f, 0.f};
    for (int k0 = 0; k0 < K; k0 += 32) {
        short8 af = *reinterpret_cast<const short8*>(&xs[ln * stride + k0 + quad * 8]);
        short8 b0 = *reinterpret_cast<const short8*>(&wT[(n0 + ln) * K + k0 + quad * 8]);
        short8 b1 = *reinterpret_cast<const short8*>(&wT[(n0 + 16 + ln) * K + k0 + quad * 8]);
        acc0 = __builtin_amdgcn_mfma_f32_16x16x32_bf16(af, b0, acc0, 0, 0, 0);
        acc1 = __builtin_amdgcn_mfma_f32_16x16x32_bf16(af, b1, acc1, 0, 0, 0);
    }
    const float b0v = bias[n0 + ln], b1v = bias[n0 + 16 + ln];
#pragma unroll
    for (int r = 0; r < 4; ++r) {
        int row = rowbase + quad * 4 + r;
        out[(size_t)row * H + n0 + ln] = f2bf(fmaxf(acc0[r] + b0v, 0.f));
        out[(size_t)row * H + n0 + 16 + ln] = f2bf(fmaxf(acc1[r] + b1v, 0.f));
    }
}

// ---------------------------------------------------------------------------
// CSR build, pass 1: per-(chunk,bucket) histogram. scanH layout [bucket][chunk]
// ---------------------------------------------------------------------------
__global__ void histA_kernel(const int* __restrict__ e0, const int* __restrict__ e1,
                             int* __restrict__ scanH0, int* __restrict__ scanH1) {
    __shared__ int hist[NBUK];
    const int tx = threadIdx.x;
    const bool first = blockIdx.x < BCH;
    const int c = first ? blockIdx.x : blockIdx.x - BCH;
    const int* edst = (first ? e0 : e1) + NEDGE + c * CHUNK;
    int* scanH = first ? scanH0 : scanH1;

    for (int i = tx; i < NBUK; i += 256) hist[i] = 0;
    __syncthreads();
    for (int e = tx; e < CHUNK; e += 256) atomicAdd(&hist[edst[e] >> 6], 1);
    __syncthreads();
    for (int i = tx; i < NBUK; i += 256) scanH[i * BCH + c] = hist[i];
}

// ---------------------------------------------------------------------------
// exclusive scan over SCANH_N elems, in-place, two arrays; bsum gets RAW sums
// ---------------------------------------------------------------------------
__global__ void scan1_kernel(const int* __restrict__ cnt1, int* __restrict__ off1, int* __restrict__ bsum1,
                             const int* __restrict__ cnt2, int* __restrict__ off2, int* __restrict__ bsum2,
                             int N) {
    __shared__ int tmp[256];
    const bool first = blockIdx.x < NB;
    const int blk = first ? blockIdx.x : blockIdx.x - NB;
    const int* cnt = first ? cnt1 : cnt2;
    int* off = first ? off1 : off2;
    int* bsum = first ? bsum1 : bsum2;
    const int tx = threadIdx.x;
    const int base = blk * 1024;
    int v[4];
    int s = 0;
#pragma unroll
    for (int k = 0; k < 4; ++k) {
        int i = base + tx * 4 + k;
        v[k] = (i < N) ? cnt[i] : 0;
        s += v[k];
    }
    tmp[tx] = s;
    __syncthreads();
    for (int o = 1; o < 256; o <<= 1) {
        int t = (tx >= o) ? tmp[tx - o] : 0;
        __syncthreads();
        tmp[tx] += t;
        __syncthreads();
    }
    int excl = (tx == 0) ? 0 : tmp[tx - 1];
#pragma unroll
    for (int k = 0; k < 4; ++k) {
        int i = base + tx * 4 + k;
        if (i < N) off[i] = excl;
        excl += v[k];
    }
    if (tx == 255) bsum[blk] = tmp[255];
}

// 1-wave exclusive scan of the 49 raw block sums into bpre[64] (LDS)
static __device__ __forceinline__ void bsum_scan(const int* __restrict__ bsum, int* bpre, int tx) {
    if (tx < 64) {
        int v = (tx < NB) ? bsum[tx] : 0;
        int incl = v;
#pragma unroll
        for (int o = 1; o < 64; o <<= 1) {
            int t = __shfl_up(incl, o, 64);
            if (tx >= o) incl += t;
        }
        bpre[tx] = incl - v;
    }
}

// ---------------------------------------------------------------------------
// CSR build, pass 2: scatter packed (dst<<16 | src) into per-(bucket,chunk)
// exclusive sub-ranges
// ---------------------------------------------------------------------------
__global__ void scatterA_kernel(const int* __restrict__ e0, const int* __restrict__ e1,
                                const int* __restrict__ scanH0, const int* __restrict__ bsum0,
                                const int* __restrict__ scanH1, const int* __restrict__ bsum1,
                                uintT* __restrict__ stage0, uintT* __restrict__ stage1) {
    __shared__ int cur[NBUK];
    __shared__ int bpre[64];
    const int tx = threadIdx.x;
    const bool first = blockIdx.x < BCH;
    const int c = first ? blockIdx.x : blockIdx.x - BCH;
    const int* ei = first ? e0 : e1;
    const int* scanH = first ? scanH0 : scanH1;
    const int* bsum = first ? bsum0 : bsum1;
    uintT* stage = first ? stage0 : stage1;

    bsum_scan(bsum, bpre, tx);
    __syncthreads();
    for (int i = tx; i < NBUK; i += 256) {
        int idx = i * BCH + c;
        cur[i] = scanH[idx] + bpre[idx >> 10];
    }
    __syncthreads();
    const int base = c * CHUNK;
    for (int e = tx; e < CHUNK; e += 256) {
        int s = ei[base + e];
        int d = ei[NEDGE + base + e];
        int pos = atomicAdd(&cur[d >> 6], 1);
        stage[pos] = ((uintT)d << 16) | (uintT)s;
    }
}

// ---------------------------------------------------------------------------
// CSR build, pass 3: per-bucket local sort by dst; dense u16 srcidx + off[]
// ---------------------------------------------------------------------------
__global__ void passB_kernel(const uintT* __restrict__ stage0, const int* __restrict__ scanH0,
                             const int* __restrict__ bsum0, ushortT* __restrict__ srcidx0,
                             int* __restrict__ off0,
                             const uintT* __restrict__ stage1, const int* __restrict__ scanH1,
                             const int* __restrict__ bsum1, ushortT* __restrict__ srcidx1,
                             int* __restrict__ off1) {
    __shared__ uintT inbuf[BCAP];
    __shared__ ushortT outbuf[BCAP];
    __shared__ int hist[64], scn[64], cur[64];
    __shared__ int bpre[64];
    const int tx = threadIdx.x;
    const bool first = blockIdx.x < NBUK;
    const int b = first ? blockIdx.x : blockIdx.x - NBUK;
    const uintT* stage = first ? stage0 : stage1;
    const int* scanH = first ? scanH0 : scanH1;
    const int* bsum = first ? bsum0 : bsum1;
    ushortT* srcidx = first ? srcidx0 : srcidx1;
    int* off = first ? off0 : off1;

    bsum_scan(bsum, bpre, tx);
    if (tx >= 64 && tx < 128) hist[tx - 64] = 0;
    __syncthreads();

    const int ib = b * BCH;                       // == b*64
    const int base = scanH[ib] + bpre[ib >> 10];
    const int end = (b == NBUK - 1) ? NEDGE : (scanH[ib + BCH] + bpre[(ib + BCH) >> 10]);
    const int size = end - base;

    for (int i = tx; i < size; i += 256) inbuf[i] = stage[base + i];
    __syncthreads();
    for (int i = tx; i < size; i += 256) atomicAdd(&hist[(inbuf[i] >> 16) & 63], 1);
    __syncthreads();
    if (tx == 0) {
        int s = 0;
#pragma unroll
        for (int i = 0; i < 64; ++i) { scn[i] = s; s += hist[i]; }
    }
    __syncthreads();
    if (tx < 64) cur[tx] = scn[tx];
    __syncthreads();
    for (int i = tx; i < size; i += 256) {
        uintT w = inbuf[i];
        int pos = atomicAdd(&cur[(w >> 16) & 63], 1);
        outbuf[pos] = (ushortT)(w & 0xffffu);
    }
    __syncthreads();
    for (int i = tx; i < size; i += 256) srcidx[base + i] = outbuf[i];
    if (tx < 64) {
        int d = b * 64 + tx;
        if (d < NNODE) off[d] = base + scn[tx];
    }
    if (b == NBUK - 1 && tx == 64) off[NNODE] = NEDGE;
}

// ---------------------------------------------------------------------------
// merged SAGE pair — fused gather + MFMA. Gather: srcidx slice staged in LDS
// (CSR-contiguous per 16-row block), unroll-16 masked row loads with
// readfirstlane-scalarized indices (SGPR base + lane offset addressing).
// ---------------------------------------------------------------------------
#define GATHER_LOOP(READIDX)                                                   \
    for (int j = 0; j < deg; j += 16) {                                        \
        uintT vv[16];                                                          \
        float mm[16];                                                          \
        _Pragma("unroll")                                                      \
        for (int k = 0; k < 16; ++k) {                                         \
            int e = j + k;                                                     \
            int ec = (e < deg) ? e : deg - 1;                                  \
            int s = __builtin_amdgcn_readfirstlane(READIDX(ec));               \
            const uintT* rp = src32 + ((size_t)(uintT)s << 6);                 \
            vv[k] = rp[lane];                                                  \
            mm[k] = (e < deg) ? 1.f : 0.f;                                     \
        }                                                                      \
        _Pragma("unroll")                                                      \
        for (int k = 0; k < 16; ++k) {                                         \
            a0 = fmaf(lo2f(vv[k]), mm[k], a0);                                 \
            a1 = fmaf(hi2f(vv[k]), mm[k], a1);                                 \
        }                                                                      \
    }

__global__ void sage2_kernel(
    const ushortT* __restrict__ xsrcA, const ushortT* __restrict__ srcA,
    const int* __restrict__ offA,
    const ushortT* __restrict__ xdstA, const ushortT* __restrict__ wlTA,
    const float* __restrict__ blA, const ushortT* __restrict__ wrTA, ushortT* __restrict__ outA,
    const ushortT* __restrict__ xsrcB, const ushortT* __restrict__ srcB,
    const int* __restrict__ offB,
    const ushortT* __restrict__ xdstB, const ushortT* __restrict__ wlTB,
    const float* __restrict__ blB, const ushortT* __restrict__ wrTB, ushortT* __restrict__ outB) {
    __shared__ ushortT At[16 * 264];
    __shared__ ushortT idxbuf[IDXCAP];
    __shared__ float part[4][16];
    __shared__ float scl[16];
    const bool first = blockIdx.x < NBLK16;
    const int blk = first ? blockIdx.x : blockIdx.x - NBLK16;
    const ushortT* xsrc = first ? xsrcA : xsrcB;
    const ushortT* srcidx = first ? srcA : srcB;
    const int* off      = first ? offA  : offB;
    const ushortT* xdst = first ? xdstA : xdstB;
    const ushortT* wlT  = first ? wlTA  : wlTB;
    const float* bl     = first ? blA   : blB;
    const ushortT* wrT  = first ? wrTA  : wrTB;
    ushortT* out        = first ? outA  : outB;

    const int tx = threadIdx.x;
    const int rowbase = blk * 16;
    const int wave = tx >> 6, lane = tx & 63;

    {   // stage xdst tile into k-slots 128..255
        int r = tx >> 4, ch = tx & 15;
        *reinterpret_cast<short8*>(&At[r * 264 + 128 + ch * 8]) =
            *reinterpret_cast<const short8*>(&xdst[(size_t)(rowbase + r) * H + ch * 8]);
    }
    // stage this block's CSR srcidx slice (contiguous) into LDS
    const int base0 = __builtin_amdgcn_readfirstlane(off[rowbase]);
    const int total = __builtin_amdgcn_readfirstlane(off[rowbase + 16]) - base0;
    const int nst = total < IDXCAP ? total : IDXCAP;
    for (int i = tx; i < nst; i += 256) idxbuf[i] = srcidx[base0 + i];
    __syncthreads();

    // gather-mean: 4 rows per wave, serial; 16 row-loads in flight per row
    const uintT* src32 = (const uintT*)xsrc;
#pragma unroll
    for (int rr = 0; rr < 4; ++rr) {
        const int r = wave * 4 + rr;
        const int row = rowbase + r;
        const int start = __builtin_amdgcn_readfirstlane(off[row]);
        const int deg = __builtin_amdgcn_readfirstlane(off[row + 1]) - start;
        const int loc = start - base0;
        float a0 = 0.f, a1 = 0.f;
        if (loc + deg <= IDXCAP) {
            GATHER_LOOP([&](int ec) { return (int)idxbuf[loc + ec]; })
        } else {
            GATHER_LOOP([&](int ec) { return (int)srcidx[start + ec]; })
        }
        float inv = 1.f / fmaxf((float)deg, 1.f);
        *reinterpret_cast<uintT*>(&At[r * 264 + lane * 2]) = pack2(a0 * inv, a1 * inv);
    }
    __syncthreads();

    // MFMA: wave w -> cols [32w, 32w+32)
    const int ln = lane & 15, quad = lane >> 4;
    const int n0 = wave * 32;
    floatx4 acc0 = {0.f, 0.f, 0.f, 0.f};
    floatx4 acc1 = {0.f, 0.f, 0.f, 0.f};
#pragma unroll
    for (int k0 = 0; k0 < 256; k0 += 32) {
        short8 af = *reinterpret_cast<const short8*>(&At[ln * 264 + k0 + quad * 8]);
        const ushortT* wT = (k0 < 128) ? wlT : wrT;
        const int kk = (k0 & 127) + quad * 8;
        short8 b0 = *reinterpret_cast<const short8*>(&wT[(n0 + ln) * 128 + kk]);
        short8 b1 = *reinterpret_cast<const short8*>(&wT[(n0 + 16 + ln) * 128 + kk]);
        acc0 = __builtin_amdgcn_mfma_f32_16x16x32_bf16(af, b0, acc0, 0, 0, 0);
        acc1 = __builtin_amdgcn_mfma_f32_16x16x32_bf16(af, b1, acc1, 0, 0, 0);
    }

    // epilogue: bias, row L2-norm, relu, residual(+xdst), bf16 store
    const float bl0 = bl[n0 + ln];
    const float bl1 = bl[n0 + 16 + ln];
    float v0[4], v1[4], s[4];
#pragma unroll
    for (int r = 0; r < 4; ++r) {
        v0[r] = acc0[r] + bl0;
        v1[r] = acc1[r] + bl1;
        s[r] = v0[r] * v0[r] + v1[r] * v1[r];
    }
#pragma unroll
    for (int m = 1; m < 16; m <<= 1) {
#pragma unroll
        for (int r = 0; r < 4; ++r) s[r] += __shfl_xor(s[r], m, 64);
    }
    if (ln == 0) {
#pragma unroll
        for (int r = 0; r < 4; ++r) part[wave][quad * 4 + r] = s[r];
    }
    __syncthreads();
    if (tx < 16) {
        float t = part[0][tx] + part[1][tx] + part[2][tx] + part[3][tx];
        scl[tx] = 1.f / fmaxf(sqrtf(t), 1e-12f);
    }
    __syncthreads();
#pragma unroll
    for (int r = 0; r < 4; ++r) {
        const int row = quad * 4 + r;
        const float sc = scl[row];
        float o0 = fmaxf(v0[r] * sc, 0.f) + bf2f(At[row * 264 + 128 + n0 + ln]);
        float o1 = fmaxf(v1[r] * sc, 0.f) + bf2f(At[row * 264 + 128 + n0 + 16 + ln]);
        out[(size_t)(rowbase + row) * H + n0 + ln] = f2bf(o0);
        out[(size_t)(rowbase + row) * H + n0 + 16 + ln] = f2bf(o1);
    }
}

// ---------------------------------------------------------------------------
// head (MFMA GEMM1 + small fp32 GEMM2)
// ---------------------------------------------------------------------------
__global__ void head_kernel(const ushortT* __restrict__ hu, const ushortT* __restrict__ w1T,
                            const float* __restrict__ b1, const float* __restrict__ w2,
                            const float* __restrict__ b2, float* __restrict__ out) {
    __shared__ ushortT hs[16 * 136];
    __shared__ float zs[16 * 72];
    const int tx = threadIdx.x;
    const int rowbase = blockIdx.x * 16;
    {
        int r = tx >> 4, ch = tx & 15;
        *reinterpret_cast<short8*>(&hs[r * 136 + ch * 8]) =
            *reinterpret_cast<const short8*>(&hu[(size_t)(rowbase + r) * H + ch * 8]);
    }
    __syncthreads();
    const int wave = tx >> 6, lane = tx & 63;
    const int ln = lane & 15, quad = lane >> 4;
    floatx4 acc = {0.f, 0.f, 0.f, 0.f};
#pragma unroll
    for (int k0 = 0; k0 < 128; k0 += 32) {
        short8 af = *reinterpret_cast<const short8*>(&hs[ln * 136 + k0 + quad * 8]);
        short8 bf = *reinterpret_cast<const short8*>(&w1T[(wave * 16 + ln) * 128 + k0 + quad * 8]);
        acc = __builtin_amdgcn_mfma_f32_16x16x32_bf16(af, bf, acc, 0, 0, 0);
    }
    const float bv = b1[wave * 16 + ln];
#pragma unroll
    for (int r = 0; r < 4; ++r)
        zs[(quad * 4 + r) * 72 + wave * 16 + ln] = fmaxf(acc[r] + bv, 0.f);
    __syncthreads();
    if (tx < 128) {
        int r = tx >> 3, c = tx & 7;
        float a = b2[c];
#pragma unroll 8
        for (int k = 0; k < 64; ++k) a += zs[r * 72 + k] * w2[k * 8 + c];
        out[(size_t)(rowbase + r) * 8 + c] = a;
    }
}

// ---------------------------------------------------------------------------
extern "C" void kernel_launch(void* const* d_in, const int* in_sizes, int n_in,
                              void* d_out, int out_size, void* d_ws, size_t ws_size,
                              hipStream_t stream) {
    const float* x_user     = (const float*)d_in[0];
    const float* x_item     = (const float*)d_in[1];
    const int*   ei_u2i     = (const int*)d_in[2];
    const int*   ei_i2u     = (const int*)d_in[3];
    const float* enc_user_w = (const float*)d_in[4];
    const float* enc_user_b = (const float*)d_in[5];
    const float* enc_item_w = (const float*)d_in[6];
    const float* enc_item_b = (const float*)d_in[7];
    const float* W[12];
    for (int i = 0; i < 12; ++i) W[i] = (const float*)d_in[8 + i];
    const float* head_w1 = (const float*)d_in[20];
    const float* head_b1 = (const float*)d_in[21];
    const float* head_w2 = (const float*)d_in[22];
    const float* head_b2 = (const float*)d_in[23];
    float* out = (float*)d_out;

    const size_t S = (size_t)NNODE * H;
    ushortT* huA  = (ushortT*)d_ws;
    ushortT* huB  = huA + S;
    ushortT* hiA  = huB + S;
    ushortT* hiB  = hiA + S;
    ushortT* wT   = hiB + S;                  // 151552 bf16
    int*    scanH_i = (int*)(wT + 151552);    // [SCANH_N]
    int*    scanH_u = scanH_i + SCANH_N;
    int*    bsum_i  = scanH_u + SCANH_N;      // [64] raw block sums
    int*    bsum_u  = bsum_i + 64;
    int*    off_i   = bsum_u + 64;            // [NNODE+1]
    int*    off_u   = off_i + NNODE + 1;
    uintT*  stage_i = (uintT*)(off_u + NNODE + 1);  // [NEDGE]
    uintT*  stage_u = stage_i + NEDGE;
    ushortT* src_i  = (ushortT*)(stage_u + NEDGE);  // [NEDGE] u16
    ushortT* src_u  = src_i + NEDGE;

    const ushortT* wTeu = wT + 131072;
    const ushortT* wTei = wT + 139264;
    const ushortT* w1T  = wT + 143360;

    convert_all_kernel<<<592, 256, 0, stream>>>(
        W[0], W[2], W[3], W[5], W[6], W[8], W[9], W[11],
        enc_user_w, enc_item_w, head_w1, wT);

    encode2_kernel<<<2 * NBLK16, 256, 0, stream>>>(
        x_user, wTeu, enc_user_b, x_item, wTei, enc_item_b, huA, hiA);

    // CSR build: hist -> scan -> locality-preserving scatter -> local sort
    histA_kernel<<<2 * BCH, 256, 0, stream>>>(ei_u2i, ei_i2u, scanH_i, scanH_u);
    scan1_kernel<<<2 * NB, 256, 0, stream>>>(scanH_i, scanH_i, bsum_i,
                                             scanH_u, scanH_u, bsum_u, SCANH_N);
    scatterA_kernel<<<2 * BCH, 256, 0, stream>>>(ei_u2i, ei_i2u, scanH_i, bsum_i,
                                                 scanH_u, bsum_u, stage_i, stage_u);
    passB_kernel<<<2 * NBUK, 256, 0, stream>>>(stage_i, scanH_i, bsum_i, src_i, off_i,
                                               stage_u, scanH_u, bsum_u, src_u, off_u);

    // layer 0: new_hi=f(huA,hiA)->hiB ; new_hu=f(hiA,huA)->huB
    sage2_kernel<<<2 * NBLK16, 256, 0, stream>>>(
        huA, src_i, off_i, hiA, wT + 0 * 16384, W[1], wT + 1 * 16384, hiB,
        hiA, src_u, off_u, huA, wT + 2 * 16384, W[4], wT + 3 * 16384, huB);

    // layer 1: new_hi=f(huB,hiB)->hiA ; new_hu=f(hiB,huB)->huA
    sage2_kernel<<<2 * NBLK16, 256, 0, stream>>>(
        huB, src_i, off_i, hiB, wT + 4 * 16384, W[7], wT + 5 * 16384, hiA,
        hiB, src_u, off_u, huB, wT + 6 * 16384, W[10], wT + 7 * 16384, huA);

    head_kernel<<<NBLK16, 256, 0, stream>>>(huA, w1T, head_b1, head_w2, head_b2, out);
}